// Round 3
// baseline (208.703 us; speedup 1.0000x reference)
//
#include <hip/hip_runtime.h>
#include <stdint.h>

typedef unsigned short u16;
typedef unsigned int   u32;
typedef __attribute__((ext_vector_type(8))) short bf16x8;  // 8 bf16 = 4 VGPR
typedef __attribute__((ext_vector_type(4))) short bf16x4;  // 4 bf16 = 2 VGPR
typedef __attribute__((ext_vector_type(4))) float f32x4;   // MFMA C/D frag
typedef __attribute__((ext_vector_type(16))) float f32x16; // 32x32 MFMA C/D frag

#define NT ((size_t)8388608)   // 32*1024*256 elements

// ---------- helpers ----------
__device__ __forceinline__ float bf2f(u16 u) {
  union { float f; u32 i; } v; v.i = ((u32)u) << 16; return v.f;
}
__device__ __forceinline__ u16 f2bf(float f) {
  union { float f; u32 i; } v; v.f = f;
  u32 r = (v.i + 0x7fffu + ((v.i >> 16) & 1u)) >> 16;   // RNE
  return (u16)r;
}
__device__ __forceinline__ u32 fbits(float f) {
  union { float f; u32 i; } v; v.f = f; return v.i;
}
// bf16-vs-f32 buffer sniff (64-lane ballot on exponent-byte position)
__device__ __forceinline__ int detect_bf16(const u32* __restrict__ xd) {
  u32 w = xd[threadIdx.x & 63];
  u32 e = (w >> 8) & 0x7fu;
  unsigned long long m = __ballot((e >= 0x38u) && (e <= 0x41u));
  return __popcll(m) > 32;
}
// async 16B/lane global->LDS (dest = wave-uniform base + lane*16)
__device__ __forceinline__ void gld16(const void* g, void* l) {
  __builtin_amdgcn_global_load_lds((const __attribute__((address_space(1))) u32*)g,
                                   (__attribute__((address_space(3))) u32*)l, 16, 0, 0);
}

// ---------- prologue: x transpose (0..2047) + Wq/Wk/Wv prep (2048..2239) + optional Wo (2240..2303) ----------
__global__ void __launch_bounds__(256) prologue_kernel(const void* __restrict__ xin,
                                                       u16* __restrict__ xT,
                                                       const void* __restrict__ W0, const void* __restrict__ W1,
                                                       const void* __restrict__ W2, const void* __restrict__ b0,
                                                       const void* __restrict__ b1, const void* __restrict__ b2,
                                                       u16* __restrict__ wdst, float* __restrict__ bdst,
                                                       const void* __restrict__ Wo, const void* __restrict__ bo,
                                                       const void* __restrict__ gm, u16* __restrict__ wodst,
                                                       float* __restrict__ bodst) {
  const int blk = blockIdx.x;
  const int tid = threadIdx.x;
  const int isbf = detect_bf16((const u32*)xin);
  if (blk < 2048) {
    const int s0 = (blk & 15) * 64, c0 = ((blk >> 4) & 3) * 64, b = blk >> 6;
    __shared__ u16 T[64][72];  // [c-local][s-local], +8 pad
    if (isbf) {
      const u16* xp = (const u16*)xin;
      for (int t = tid; t < 512; t += 256) {
        int r = t >> 3, off = (t & 7) * 8;
        *(uint4*)&T[r][off] = *(const uint4*)(xp + ((size_t)(b * 256 + c0 + r)) * 1024 + s0 + off);
      }
    } else {
      const float* xp = (const float*)xin;
      for (int t = tid; t < 512; t += 256) {
        int r = t >> 3, off = (t & 7) * 8;
        const float* s = xp + ((size_t)(b * 256 + c0 + r)) * 1024 + s0 + off;
#pragma unroll
        for (int u = 0; u < 8; u++) T[r][off + u] = f2bf(s[u]);
      }
    }
    __syncthreads();
    for (int t = tid; t < 512; t += 256) {
      int r = t >> 3, off = (t & 7) * 8;   // r = s-local, off = c-local
      union { u16 h[8]; uint4 v; } pk;
#pragma unroll
      for (int u = 0; u < 8; u++) pk.h[u] = T[off + u][r];
      *(uint4*)(xT + ((size_t)(b * 1024 + s0 + r)) * 256 + c0 + off) = pk.v;
    }
  } else if (blk < 2240) {
    const int g = blk - 2048;            // 192 blocks: 64 per weight
    const int which = g >> 6, bk = g & 63;
    const void* Ws = which == 0 ? W0 : which == 1 ? W1 : W2;
    const void* bs = which == 0 ? b0 : which == 1 ? b1 : b2;
    const int idx = bk * 1024 + tid * 4;
    u16* dst = wdst + which * 65536 + idx;
    if (isbf) {
      *(ushort4*)dst = *(const ushort4*)((const u16*)Ws + idx);
    } else {
      const float* s = (const float*)Ws + idx;
      ushort4 o; o.x = f2bf(s[0]); o.y = f2bf(s[1]); o.z = f2bf(s[2]); o.w = f2bf(s[3]);
      *(ushort4*)dst = o;
    }
    if (bk == 0) {
      bdst[which * 256 + tid] = isbf ? bf2f(((const u16*)bs)[tid]) : ((const float*)bs)[tid];
    }
  } else {
    const int g = blk - 2240;            // 64 blocks: Wo
    const int idx = g * 1024 + tid * 4;
    if (isbf) {
      *(ushort4*)(wodst + idx) = *(const ushort4*)((const u16*)Wo + idx);
    } else {
      const float* s = (const float*)Wo + idx;
      ushort4 o; o.x = f2bf(s[0]); o.y = f2bf(s[1]); o.z = f2bf(s[2]); o.w = f2bf(s[3]);
      *(ushort4*)(wodst + idx) = o;
    }
    if (g == 0) {
      bodst[tid] = isbf ? bf2f(((const u16*)bo)[tid]) : ((const float*)bo)[tid];
      if (tid == 0) bodst[256] = isbf ? bf2f(((const u16*)gm)[0]) : ((const float*)gm)[0];
    }
  }
}

// ---------- Wo prep fallback (when ws tail unavailable; runs after attn) ----------
__global__ void __launch_bounds__(256) prep_o(const void* __restrict__ Wo, const void* __restrict__ bo,
                                              const void* __restrict__ gm, u16* __restrict__ wdst,
                                              float* __restrict__ bdst, const u32* __restrict__ xdet) {
  const int isbf = detect_bf16(xdet);
  const int idx = blockIdx.x * 1024 + threadIdx.x * 4;
  if (isbf) {
    *(ushort4*)(wdst + idx) = *(const ushort4*)((const u16*)Wo + idx);
  } else {
    const float* s = (const float*)Wo + idx;
    ushort4 o; o.x = f2bf(s[0]); o.y = f2bf(s[1]); o.z = f2bf(s[2]); o.w = f2bf(s[3]);
    *(ushort4*)(wdst + idx) = o;
  }
  if (blockIdx.x == 0) {
    int t = threadIdx.x;
    bdst[t] = isbf ? bf2f(((const u16*)bo)[t]) : ((const float*)bo)[t];
    if (t == 0) bdst[256] = isbf ? bf2f(((const u16*)gm)[0]) : ((const float*)gm)[0];
  }
}

// ---------- fused QKV projection, BK=64: one launch, z = b*3 + which ----------
// Q and K are written HEAD-PACKED: (b, h, s, 32) so attn reads per-(b,h)
// contiguous 64KB blocks (full cache-line efficiency + compact L2 footprint).
// V stays (b, c, s) which is already (b, h, dh, s)-contiguous.
__global__ void __launch_bounds__(256) qkv_gemm(const u16* __restrict__ xT,
                                                const u16* __restrict__ Wall,
                                                const float* __restrict__ ball,
                                                u16* __restrict__ Qb, u16* __restrict__ Kb,
                                                u16* __restrict__ Vb) {
  const int z = blockIdx.z, b = z / 3, which = z - b * 3;
  const int tid = threadIdx.x, lane = tid & 63, wave = tid >> 6;
  const int quad = lane >> 4, l16 = lane & 15;
  const int wm = wave >> 1, wn = wave & 1;
  const u16* xb = xT + (size_t)b * 262144;
  const u16* W = Wall + which * 65536;
  int m0, n0; const u16 *Abase, *Bbase;
  if (which < 2) { m0 = blockIdx.y * 128; n0 = blockIdx.x * 128; Abase = xb; Bbase = W; }
  else           { m0 = blockIdx.x * 128; n0 = blockIdx.y * 128; Abase = W; Bbase = xb; }

  __shared__ u16 Ash[8192], Bsh[8192];   // 128 rows x 64 (128B rows), k-granule swizzled
  f32x4 acc[4][4];
#pragma unroll
  for (int i = 0; i < 4; i++)
#pragma unroll
    for (int j = 0; j < 4; j++) acc[i][j] = (f32x4){0.f, 0.f, 0.f, 0.f};

  const int srow = lane >> 3;
  const int sgc = (lane & 7) ^ (srow & 7);   // pre-swizzled source k-granule
  for (int k0 = 0; k0 < 256; k0 += 64) {
    __syncthreads();   // WAR: prior frag reads done before restage lands
#pragma unroll
    for (int p = 0; p < 4; p++) {
      const int row = p * 32 + wave * 8;
      gld16(Abase + (size_t)(m0 + row + srow) * 256 + k0 + sgc * 8, &Ash[row * 64 + lane * 8]);
      gld16(Bbase + (size_t)(n0 + row + srow) * 256 + k0 + sgc * 8, &Bsh[row * 64 + lane * 8]);
    }
    __syncthreads();   // drains vmcnt before barrier
#pragma unroll
    for (int kk = 0; kk < 2; kk++) {
      bf16x8 av[4], bv[4];
      const int rg = (kk * 4 + quad) ^ (l16 & 7);   // swizzled read granule
#pragma unroll
      for (int i = 0; i < 4; i++) av[i] = *(const bf16x8*)&Ash[(wm * 64 + i * 16 + l16) * 64 + rg * 8];
#pragma unroll
      for (int j = 0; j < 4; j++) bv[j] = *(const bf16x8*)&Bsh[(wn * 64 + j * 16 + l16) * 64 + rg * 8];
#pragma unroll
      for (int i = 0; i < 4; i++)
#pragma unroll
        for (int j = 0; j < 4; j++)
          acc[i][j] = __builtin_amdgcn_mfma_f32_16x16x32_bf16(av[i], bv[j], acc[i][j], 0, 0, 0);
    }
  }

  const float* bias = ball + which * 256;
  const float scale = (which == 0) ? 0.25503486f : 1.0f;  // (1/sqrt(32))*log2(e) folded into Q
#pragma unroll
  for (int i = 0; i < 4; i++) {
#pragma unroll
    for (int j = 0; j < 4; j++) {
      const int mb = m0 + wm * 64 + i * 16 + quad * 4;
      const int n = n0 + wn * 64 + j * 16 + l16;
#pragma unroll
      for (int r = 0; r < 4; r++) {
        const int m = mb + r;
        float v = acc[i][j][r];
        if (which < 2) {
          v = (v + bias[n]) * scale;
          u16* D = (which ? Kb : Qb) + (size_t)b * 262144;
          // head-packed: (h, s, dh)
          D[(size_t)(n >> 5) * 32768 + (size_t)m * 32 + (n & 31)] = f2bf(v);
        } else {
          v = v + bias[m];
          (Vb + (size_t)b * 262144)[(size_t)m * 1024 + n] = f2bf(v);
        }
      }
    }
  }
}

// ---------- fused attention v10: 32x32 MFMA, in-register P repack, swizzled dbuf LDS ----------
// vs v9: waves_per_eu attr REVERTED (R2: VGPR stayed 64, attn regressed 4%).
// Q/K now head-packed (b,h,s,32): per-(b,h) contiguous 64KB -> dense 64B-row
// reads (was 64B used of each 512B row = <=50% line efficiency, FETCH 89MB vs
// ~50MB ideal) and compact 128KB/head L2 footprint shared by all 4 q-chunks.
__global__ void __launch_bounds__(512) attn_kernel(const u16* __restrict__ Q,
                                                   const u16* __restrict__ K,
                                                   const u16* __restrict__ V,
                                                   u16* __restrict__ O) {
  const int blk = blockIdx.x;
  const int qc = blk >> 8, bh = blk & 255;
  const int b = bh >> 3, h = bh & 7;
  const int tid = threadIdx.x, wave = tid >> 6, lane = tid & 63;
  const int hi = lane >> 5, l32 = lane & 31;
  __shared__ __align__(16) u16 Ksh[2][128 * 32];  // [t][d] granule-swizzled
  __shared__ __align__(16) u16 Vsh[2][32 * 128];  // [d][t] granule col ^= (d&15)
  const u16* Qg = Q + (size_t)b * 262144 + (size_t)h * 32768;  // (b,h,s,32)
  const u16* Kg = K + (size_t)b * 262144 + (size_t)h * 32768;  // (b,h,s,32)
  const u16* Vg = V + (size_t)b * 262144 + (size_t)h * 32768;  // (b,h,dh,s)
  const int qw = qc * 256 + wave * 32;   // this wave's 32 q rows

  // Q frags (B-operand): lane n=l32 holds Q[q=qw+l32][d = ks*16 + hi*8 + j]
  bf16x8 qf[2];
#pragma unroll
  for (int ks = 0; ks < 2; ks++)
    qf[ks] = *(const bf16x8*)(Qg + (size_t)(qw + l32) * 32 + ks * 16 + hi * 8);

  // K staging: this lane's granule Gg; location Gg must hold K[t(Gg)][8*s(Gg)..+7]
  const int Gg = wave * 64 + lane;
  const int th = Gg >> 3;
  const int uu = (Gg & 7) ^ (th & 7);
  const u16* ksrc = Kg + (size_t)(th * 2 + (uu >> 2)) * 32 + (uu & 3) * 8;
  u16* kdst0 = &Ksh[0][Gg * 8];
  u16* kdst1 = &Ksh[1][Gg * 8];
  // V staging: granule tid holds V[d = tid>>4][8*((tid&15)^(d&15)) ..+7]
  const int vd = tid >> 4;
  const u16* vsrc = Vg + (size_t)vd * 1024 + ((tid & 15) ^ (vd & 15)) * 8;
  u16* vdst0 = &Vsh[0][tid * 8];
  u16* vdst1 = &Vsh[1][tid * 8];

  // kf read byte-offsets (A-operand, lane m = t = tt*32+l32, k-half ks): +tt*2048
  const int kkey = (l32 >> 1) & 7;
  const int kb0 = (l32 >> 1) * 128 + (((((l32 & 1) << 2) | 0 | hi) ^ kkey) << 4);
  const int kb1 = (l32 >> 1) * 128 + (((((l32 & 1) << 2) | 2 | hi) ^ kkey) << 4);
  // vf read byte-offsets: l32*256 + ((tg ^ (l32&15))<<4), tg = 4*tt + 2*m + hi
  int vb[4];
#pragma unroll
  for (int tt = 0; tt < 4; tt++) vb[tt] = l32 * 256 + (((l32 & 12) ^ (tt << 2)) << 4);
  const int vm0 = ((l32 & 3) ^ hi) << 4;
  const int vm1 = ((l32 & 3) ^ (2 | hi)) << 4;

  f32x16 oacc;
#pragma unroll
  for (int r = 0; r < 16; r++) oacc[r] = 0.f;
  f32x16 zro;   // persistent zero C-operand for QK^T (never written)
#pragma unroll
  for (int r = 0; r < 16; r++) zro[r] = 0.f;
  float lsum = 0.f;

  // prologue: stage tile 0
  gld16(ksrc, kdst0);
  gld16(vsrc, vdst0);
  __syncthreads();

#pragma unroll 1
  for (int kt = 0; kt < 8; kt++) {
    const int c = kt & 1;
    if (kt < 7) {   // issue next tile into the other buffer; drained at loop-end barrier
      gld16(ksrc + (size_t)(kt + 1) * 4096, c ? kdst0 : kdst1);   // 128 t-rows x 32
      gld16(vsrc + (kt + 1) * 128,          c ? vdst0 : vdst1);
    }
    const char* Kb = (const char*)&Ksh[c][0];
    const char* Vb = (const char*)&Vsh[c][0];
#pragma unroll
    for (int tt = 0; tt < 4; tt++) {
      const bf16x8 kf0 = *(const bf16x8*)(Kb + tt * 2048 + kb0);
      const bf16x8 kf1 = *(const bf16x8*)(Kb + tt * 2048 + kb1);
      const bf16x8 vf0 = *(const bf16x8*)(Vb + vb[tt] + vm0);
      const bf16x8 vf1 = *(const bf16x8*)(Vb + vb[tt] + vm1);
      __builtin_amdgcn_s_setprio(1);
      f32x16 sf = __builtin_amdgcn_mfma_f32_32x32x16_bf16(kf0, qf[0], zro, 0, 0, 0);
      sf = __builtin_amdgcn_mfma_f32_32x32x16_bf16(kf1, qf[1], sf, 0, 0, 0);
      __builtin_amdgcn_s_setprio(0);
      // ---- first 16 t of the tile (groups g0 = sf[0:3], g1 = sf[4:7]) ----
      {
        const float p0 = __builtin_amdgcn_exp2f(sf[0]);
        const float p1 = __builtin_amdgcn_exp2f(sf[1]);
        const float p2 = __builtin_amdgcn_exp2f(sf[2]);
        const float p3 = __builtin_amdgcn_exp2f(sf[3]);
        const float p4 = __builtin_amdgcn_exp2f(sf[4]);
        const float p5 = __builtin_amdgcn_exp2f(sf[5]);
        const float p6 = __builtin_amdgcn_exp2f(sf[6]);
        const float p7 = __builtin_amdgcn_exp2f(sf[7]);
        lsum += ((p0 + p1) + (p2 + p3)) + ((p4 + p5) + (p6 + p7));
        u32 wa, wb, wc, wd;
        asm("v_cvt_pk_bf16_f32 %0, %1, %2" : "=v"(wa) : "v"(p0), "v"(p1));
        asm("v_cvt_pk_bf16_f32 %0, %1, %2" : "=v"(wb) : "v"(p2), "v"(p3));
        asm("v_cvt_pk_bf16_f32 %0, %1, %2" : "=v"(wc) : "v"(p4), "v"(p5));
        asm("v_cvt_pk_bf16_f32 %0, %1, %2" : "=v"(wd) : "v"(p6), "v"(p7));
#if __has_builtin(__builtin_amdgcn_permlane32_swap)
        auto s0 = __builtin_amdgcn_permlane32_swap((int)wc, (int)wa, false, false);
        auto s1 = __builtin_amdgcn_permlane32_swap((int)wd, (int)wb, false, false);
        union { int w[4]; bf16x8 v; } pk;
        pk.w[0] = s0[1]; pk.w[1] = s1[1]; pk.w[2] = s0[0]; pk.w[3] = s1[0];
#else
        const u32 xa = __shfl_xor((int)wa, 32), xb = __shfl_xor((int)wb, 32);
        const u32 xc = __shfl_xor((int)wc, 32), xd = __shfl_xor((int)wd, 32);
        union { u32 w[4]; bf16x8 v; } pk;
        pk.w[0] = hi ? xc : wa; pk.w[1] = hi ? xd : wb;
        pk.w[2] = hi ? wc : xa; pk.w[3] = hi ? wd : xb;
#endif
        __builtin_amdgcn_s_setprio(1);
        oacc = __builtin_amdgcn_mfma_f32_32x32x16_bf16(pk.v, vf0, oacc, 0, 0, 0);
        __builtin_amdgcn_s_setprio(0);
      }
      // ---- second 16 t of the tile (groups g2 = sf[8:11], g3 = sf[12:15]) ----
      {
        const float p0 = __builtin_amdgcn_exp2f(sf[8]);
        const float p1 = __builtin_amdgcn_exp2f(sf[9]);
        const float p2 = __builtin_amdgcn_exp2f(sf[10]);
        const float p3 = __builtin_amdgcn_exp2f(sf[11]);
        const float p4 = __builtin_amdgcn_exp2f(sf[12]);
        const float p5 = __builtin_amdgcn_exp2f(sf[13]);
        const float p6 = __builtin_amdgcn_exp2f(sf[14]);
        const float p7 = __builtin_amdgcn_exp2f(sf[15]);
        lsum += ((p0 + p1) + (p2 + p3)) + ((p4 + p5) + (p6 + p7));
        u32 wa, wb, wc, wd;
        asm("v_cvt_pk_bf16_f32 %0, %1, %2" : "=v"(wa) : "v"(p0), "v"(p1));
        asm("v_cvt_pk_bf16_f32 %0, %1, %2" : "=v"(wb) : "v"(p2), "v"(p3));
        asm("v_cvt_pk_bf16_f32 %0, %1, %2" : "=v"(wc) : "v"(p4), "v"(p5));
        asm("v_cvt_pk_bf16_f32 %0, %1, %2" : "=v"(wd) : "v"(p6), "v"(p7));
#if __has_builtin(__builtin_amdgcn_permlane32_swap)
        auto s0 = __builtin_amdgcn_permlane32_swap((int)wc, (int)wa, false, false);
        auto s1 = __builtin_amdgcn_permlane32_swap((int)wd, (int)wb, false, false);
        union { int w[4]; bf16x8 v; } pk;
        pk.w[0] = s0[1]; pk.w[1] = s1[1]; pk.w[2] = s0[0]; pk.w[3] = s1[0];
#else
        const u32 xa = __shfl_xor((int)wa, 32), xb = __shfl_xor((int)wb, 32);
        const u32 xc = __shfl_xor((int)wc, 32), xd = __shfl_xor((int)wd, 32);
        union { u32 w[4]; bf16x8 v; } pk;
        pk.w[0] = hi ? xc : wa; pk.w[1] = hi ? xd : wb;
        pk.w[2] = hi ? wc : xa; pk.w[3] = hi ? wd : xb;
#endif
        __builtin_amdgcn_s_setprio(1);
        oacc = __builtin_amdgcn_mfma_f32_32x32x16_bf16(pk.v, vf1, oacc, 0, 0, 0);
        __builtin_amdgcn_s_setprio(0);
      }
    }
    if (kt < 7) __syncthreads();   // drains vmcnt (prefetch) + WAR for restage
  }

  // epilogue: row-sums (lane + its hi-partner), scale, store
  lsum += __shfl_xor(lsum, 32);
  const float linv = 1.0f / lsum;            // valid at lane for q = l32
  u16* Og = O + (size_t)(b * 1024 + qw) * 256 + h * 32 + l32;
#pragma unroll
  for (int r = 0; r < 16; r++) {
    const int qo = (r & 3) + 8 * (r >> 2) + 4 * hi;   // oacc row -> q offset
    const float li = __shfl(linv, qo);
    Og[(size_t)qo * 256] = f2bf(oacc[r] * li);
  }
}

// ---------- out projection + residual: out = 2x + g*(Wo.O + bo) ----------
// 64x128 tiles, grid (8,4,32) = 1024 blocks = 4/CU, k-granule XOR swizzle.
__global__ void __launch_bounds__(256) out_gemm(const u16* __restrict__ WoB,
                                                const float* __restrict__ bg,
                                                const u16* __restrict__ Ob,
                                                const void* __restrict__ xin,
                                                void* __restrict__ outp,
                                                const u32* __restrict__ xdet) {
  const int b = blockIdx.z;
  const int m0 = blockIdx.y * 64, n0 = blockIdx.x * 128;
  const int tid = threadIdx.x, lane = tid & 63, wave = tid >> 6;
  const int quad = lane >> 4, l16 = lane & 15;
  const int wm = wave >> 1, wn = wave & 1;   // per wave: 32 m x 64 n
  const int isbf = detect_bf16(xdet);
  const u16* Bb = Ob + (size_t)b * 262144;
  __shared__ u16 Ash[4096], Bsh[8192];   // A 64x64, B 128x64 (swizzled granules)
  f32x4 acc[2][4];
#pragma unroll
  for (int i = 0; i < 2; i++)
#pragma unroll
    for (int j = 0; j < 4; j++) acc[i][j] = (f32x4){0.f, 0.f, 0.f, 0.f};

  const int srow = lane >> 3;
  const int sgc = (lane & 7) ^ (srow & 7);   // pre-swizzled source k-granule
  for (int k0 = 0; k0 < 256; k0 += 64) {
    __syncthreads();
#pragma unroll
    for (int p = 0; p < 2; p++) {
      const int row = p * 32 + wave * 8;
      gld16(WoB + (size_t)(m0 + row + srow) * 256 + k0 + sgc * 8, &Ash[row * 64 + lane * 8]);
    }
#pragma unroll
    for (int p = 0; p < 4; p++) {
      const int row = p * 32 + wave * 8;
      gld16(Bb + (size_t)(n0 + row + srow) * 256 + k0 + sgc * 8, &Bsh[row * 64 + lane * 8]);
    }
    __syncthreads();
#pragma unroll
    for (int kk = 0; kk < 2; kk++) {
      bf16x8 av[2], bv[4];
      const int rg = (kk * 4 + quad) ^ (l16 & 7);   // swizzled read granule
#pragma unroll
      for (int i = 0; i < 2; i++) av[i] = *(const bf16x8*)&Ash[(wm * 32 + i * 16 + l16) * 64 + rg * 8];
#pragma unroll
      for (int j = 0; j < 4; j++) bv[j] = *(const bf16x8*)&Bsh[(wn * 64 + j * 16 + l16) * 64 + rg * 8];
#pragma unroll
      for (int i = 0; i < 2; i++)
#pragma unroll
        for (int j = 0; j < 4; j++)
          acc[i][j] = __builtin_amdgcn_mfma_f32_16x16x32_bf16(av[i], bv[j], acc[i][j], 0, 0, 0);
    }
  }

  const float g = bg[256];
#pragma unroll
  for (int i = 0; i < 2; i++) {
#pragma unroll
    for (int j = 0; j < 4; j++) {
      const int mb = m0 + wm * 32 + i * 16 + quad * 4;
      const int n = n0 + wn * 64 + j * 16 + l16;
#pragma unroll
      for (int r = 0; r < 4; r++) {
        const int m = mb + r;
        const float v = acc[i][j][r] + bg[m];
        const size_t gi = (size_t)b * 262144 + (size_t)m * 1024 + n;
        const float xv = isbf ? bf2f(((const u16*)xin)[gi]) : ((const float*)xin)[gi];
        const float res = 2.f * xv + g * v;
        if (isbf) ((u16*)outp)[gi] = f2bf(res);
        else      ((float*)outp)[gi] = res;
      }
    }
  }
}

// ---------- launcher ----------
extern "C" void kernel_launch(void* const* d_in, const int* in_sizes, int n_in,
                              void* d_out, int out_size, void* d_ws, size_t ws_size,
                              hipStream_t stream) {
  const void* x  = d_in[0];
  const void* Wq = d_in[1]; const void* bq = d_in[2];
  const void* Wk = d_in[3]; const void* bk = d_in[4];
  const void* Wv = d_in[5]; const void* bv = d_in[6];
  const void* Wo = d_in[7]; const void* bo = d_in[8];
  const void* gm = d_in[9];

  u16* ws = (u16*)d_ws;
  u16* xT = ws;            // (b,s,c) bf16; reused as O after V-proj
  u16* Qb = ws + NT;       // (b,h,s,32), scale*log2e folded
  u16* Kb = ws + 2 * NT;   // (b,h,s,32)
  u16* Vb = ws + 3 * NT;   // (b,256,s) == (b,h,dh,s)
  u16* Ob = xT;
  const u32* xdet = (const u32*)x;

  // d_out doubles as QKV-weight scratch until out_gemm rewrites it fully
  u16* WqkvB = (u16*)d_out;                              // 3 x 65536 u16
  float* bqkvF = (float*)((u16*)d_out + 196608);         // 768 f32

  // Wo scratch: ws tail if it fits (prep folded into prologue), else dead-Q fallback
  const bool tail = ws_size >= (size_t)(4 * NT + 66048) * 2;
  u16* WoB = tail ? (ws + 4 * NT) : Qb;
  float* boF = tail ? (float*)(ws + 4 * NT + 65536) : (float*)(Qb + 65536);

  prologue_kernel<<<dim3(tail ? 2304 : 2240), 256, 0, stream>>>(
      x, xT, Wq, Wk, Wv, bq, bk, bv, WqkvB, bqkvF, Wo, bo, gm, WoB, boF);
  qkv_gemm<<<dim3(2, 8, 96), 256, 0, stream>>>(xT, WqkvB, bqkvF, Qb, Kb, Vb);
  attn_kernel<<<dim3(1024), 512, 0, stream>>>(Qb, Kb, Vb, Ob);
  if (!tail) prep_o<<<dim3(64), 256, 0, stream>>>(Wo, bo, gm, WoB, boF, xdet);
  out_gemm<<<dim3(8, 4, 32), 256, 0, stream>>>(WoB, boF, Ob, x, d_out, xdet);
}

// Round 4
// 188.695 us; speedup vs baseline: 1.1060x; 1.1060x over previous
//
#include <hip/hip_runtime.h>
#include <stdint.h>

typedef unsigned short u16;
typedef unsigned int   u32;
typedef __attribute__((ext_vector_type(8))) short bf16x8;  // 8 bf16 = 4 VGPR
typedef __attribute__((ext_vector_type(4))) short bf16x4;  // 4 bf16 = 2 VGPR
typedef __attribute__((ext_vector_type(4))) float f32x4;   // MFMA C/D frag
typedef __attribute__((ext_vector_type(16))) float f32x16; // 32x32 MFMA C/D frag

#define NT ((size_t)8388608)   // 32*1024*256 elements

// ---------- helpers ----------
__device__ __forceinline__ float bf2f(u16 u) {
  union { float f; u32 i; } v; v.i = ((u32)u) << 16; return v.f;
}
__device__ __forceinline__ u16 f2bf(float f) {
  union { float f; u32 i; } v; v.f = f;
  u32 r = (v.i + 0x7fffu + ((v.i >> 16) & 1u)) >> 16;   // RNE
  return (u16)r;
}
__device__ __forceinline__ u32 fbits(float f) {
  union { float f; u32 i; } v; v.f = f; return v.i;
}
// bf16-vs-f32 buffer sniff (64-lane ballot on exponent-byte position)
__device__ __forceinline__ int detect_bf16(const u32* __restrict__ xd) {
  u32 w = xd[threadIdx.x & 63];
  u32 e = (w >> 8) & 0x7fu;
  unsigned long long m = __ballot((e >= 0x38u) && (e <= 0x41u));
  return __popcll(m) > 32;
}
// async 16B/lane global->LDS (dest = wave-uniform base + lane*16)
__device__ __forceinline__ void gld16(const void* g, void* l) {
  __builtin_amdgcn_global_load_lds((const __attribute__((address_space(1))) u32*)g,
                                   (__attribute__((address_space(3))) u32*)l, 16, 0, 0);
}

// ---------- prologue: x transpose (0..2047) + Wq/Wk/Wv prep (2048..2239) + optional Wo (2240..2303) ----------
__global__ void __launch_bounds__(256) prologue_kernel(const void* __restrict__ xin,
                                                       u16* __restrict__ xT,
                                                       const void* __restrict__ W0, const void* __restrict__ W1,
                                                       const void* __restrict__ W2, const void* __restrict__ b0,
                                                       const void* __restrict__ b1, const void* __restrict__ b2,
                                                       u16* __restrict__ wdst, float* __restrict__ bdst,
                                                       const void* __restrict__ Wo, const void* __restrict__ bo,
                                                       const void* __restrict__ gm, u16* __restrict__ wodst,
                                                       float* __restrict__ bodst) {
  const int blk = blockIdx.x;
  const int tid = threadIdx.x;
  const int isbf = detect_bf16((const u32*)xin);
  if (blk < 2048) {
    const int s0 = (blk & 15) * 64, c0 = ((blk >> 4) & 3) * 64, b = blk >> 6;
    __shared__ u16 T[64][72];  // [c-local][s-local], +8 pad
    if (isbf) {
      const u16* xp = (const u16*)xin;
      for (int t = tid; t < 512; t += 256) {
        int r = t >> 3, off = (t & 7) * 8;
        *(uint4*)&T[r][off] = *(const uint4*)(xp + ((size_t)(b * 256 + c0 + r)) * 1024 + s0 + off);
      }
    } else {
      const float* xp = (const float*)xin;
      for (int t = tid; t < 512; t += 256) {
        int r = t >> 3, off = (t & 7) * 8;
        const float* s = xp + ((size_t)(b * 256 + c0 + r)) * 1024 + s0 + off;
#pragma unroll
        for (int u = 0; u < 8; u++) T[r][off + u] = f2bf(s[u]);
      }
    }
    __syncthreads();
    for (int t = tid; t < 512; t += 256) {
      int r = t >> 3, off = (t & 7) * 8;   // r = s-local, off = c-local
      union { u16 h[8]; uint4 v; } pk;
#pragma unroll
      for (int u = 0; u < 8; u++) pk.h[u] = T[off + u][r];
      *(uint4*)(xT + ((size_t)(b * 1024 + s0 + r)) * 256 + c0 + off) = pk.v;
    }
  } else if (blk < 2240) {
    const int g = blk - 2048;            // 192 blocks: 64 per weight
    const int which = g >> 6, bk = g & 63;
    const void* Ws = which == 0 ? W0 : which == 1 ? W1 : W2;
    const void* bs = which == 0 ? b0 : which == 1 ? b1 : b2;
    const int idx = bk * 1024 + tid * 4;
    u16* dst = wdst + which * 65536 + idx;
    if (isbf) {
      *(ushort4*)dst = *(const ushort4*)((const u16*)Ws + idx);
    } else {
      const float* s = (const float*)Ws + idx;
      ushort4 o; o.x = f2bf(s[0]); o.y = f2bf(s[1]); o.z = f2bf(s[2]); o.w = f2bf(s[3]);
      *(ushort4*)dst = o;
    }
    if (bk == 0) {
      bdst[which * 256 + tid] = isbf ? bf2f(((const u16*)bs)[tid]) : ((const float*)bs)[tid];
    }
  } else {
    const int g = blk - 2240;            // 64 blocks: Wo
    const int idx = g * 1024 + tid * 4;
    if (isbf) {
      *(ushort4*)(wodst + idx) = *(const ushort4*)((const u16*)Wo + idx);
    } else {
      const float* s = (const float*)Wo + idx;
      ushort4 o; o.x = f2bf(s[0]); o.y = f2bf(s[1]); o.z = f2bf(s[2]); o.w = f2bf(s[3]);
      *(ushort4*)(wodst + idx) = o;
    }
    if (g == 0) {
      bodst[tid] = isbf ? bf2f(((const u16*)bo)[tid]) : ((const float*)bo)[tid];
      if (tid == 0) bodst[256] = isbf ? bf2f(((const u16*)gm)[0]) : ((const float*)gm)[0];
    }
  }
}

// ---------- Wo prep fallback (when ws tail unavailable; runs after attn) ----------
__global__ void __launch_bounds__(256) prep_o(const void* __restrict__ Wo, const void* __restrict__ bo,
                                              const void* __restrict__ gm, u16* __restrict__ wdst,
                                              float* __restrict__ bdst, const u32* __restrict__ xdet) {
  const int isbf = detect_bf16(xdet);
  const int idx = blockIdx.x * 1024 + threadIdx.x * 4;
  if (isbf) {
    *(ushort4*)(wdst + idx) = *(const ushort4*)((const u16*)Wo + idx);
  } else {
    const float* s = (const float*)Wo + idx;
    ushort4 o; o.x = f2bf(s[0]); o.y = f2bf(s[1]); o.z = f2bf(s[2]); o.w = f2bf(s[3]);
    *(ushort4*)(wdst + idx) = o;
  }
  if (blockIdx.x == 0) {
    int t = threadIdx.x;
    bdst[t] = isbf ? bf2f(((const u16*)bo)[t]) : ((const float*)bo)[t];
    if (t == 0) bdst[256] = isbf ? bf2f(((const u16*)gm)[0]) : ((const float*)gm)[0];
  }
}

// ---------- fused QKV projection, BK=64, unified orientation: D[m=c][n=s] ----------
// A = W (rows c), B = xT (rows s) for ALL three projections. The register dim
// (quad*4+r) is now c -> for Q/K head-packed (b,h,s,32) the 4 consecutive dh
// form one contiguous ushort4 store (was 4 scalar u16 at 64B stride).
// V store (b,c,s) unchanged-scalar (n=s is the lane dim there).
__global__ void __launch_bounds__(256) qkv_gemm(const u16* __restrict__ xT,
                                                const u16* __restrict__ Wall,
                                                const float* __restrict__ ball,
                                                u16* __restrict__ Qb, u16* __restrict__ Kb,
                                                u16* __restrict__ Vb) {
  const int z = blockIdx.z, b = z / 3, which = z - b * 3;
  const int tid = threadIdx.x, lane = tid & 63, wave = tid >> 6;
  const int quad = lane >> 4, l16 = lane & 15;
  const int wm = wave >> 1, wn = wave & 1;
  const u16* xb = xT + (size_t)b * 262144;
  const u16* W = Wall + which * 65536;
  const int m0 = blockIdx.y * 128;   // c tile (2)
  const int n0 = blockIdx.x * 128;   // s tile (8)

  __shared__ u16 Ash[8192], Bsh[8192];   // 128 rows x 64 (128B rows), k-granule swizzled
  f32x4 acc[4][4];
#pragma unroll
  for (int i = 0; i < 4; i++)
#pragma unroll
    for (int j = 0; j < 4; j++) acc[i][j] = (f32x4){0.f, 0.f, 0.f, 0.f};

  const int srow = lane >> 3;
  const int sgc = (lane & 7) ^ (srow & 7);   // pre-swizzled source k-granule
  for (int k0 = 0; k0 < 256; k0 += 64) {
    __syncthreads();   // WAR: prior frag reads done before restage lands
#pragma unroll
    for (int p = 0; p < 4; p++) {
      const int row = p * 32 + wave * 8;
      gld16(W  + (size_t)(m0 + row + srow) * 256 + k0 + sgc * 8, &Ash[row * 64 + lane * 8]);
      gld16(xb + (size_t)(n0 + row + srow) * 256 + k0 + sgc * 8, &Bsh[row * 64 + lane * 8]);
    }
    __syncthreads();   // drains vmcnt before barrier
#pragma unroll
    for (int kk = 0; kk < 2; kk++) {
      bf16x8 av[4], bv[4];
      const int rg = (kk * 4 + quad) ^ (l16 & 7);   // swizzled read granule
#pragma unroll
      for (int i = 0; i < 4; i++) av[i] = *(const bf16x8*)&Ash[(wm * 64 + i * 16 + l16) * 64 + rg * 8];
#pragma unroll
      for (int j = 0; j < 4; j++) bv[j] = *(const bf16x8*)&Bsh[(wn * 64 + j * 16 + l16) * 64 + rg * 8];
#pragma unroll
      for (int i = 0; i < 4; i++)
#pragma unroll
        for (int j = 0; j < 4; j++)
          acc[i][j] = __builtin_amdgcn_mfma_f32_16x16x32_bf16(av[i], bv[j], acc[i][j], 0, 0, 0);
    }
  }

  const float* bias = ball + which * 256;
  const float scale = (which == 0) ? 0.25503486f : 1.0f;  // (1/sqrt(32))*log2(e) folded into Q
#pragma unroll
  for (int i = 0; i < 4; i++) {
#pragma unroll
    for (int j = 0; j < 4; j++) {
      const int mb = m0 + wm * 64 + i * 16 + quad * 4;   // c, 4-consecutive via r
      const int n = n0 + wn * 64 + j * 16 + l16;         // s
      if (which < 2) {
        u16* D = (which ? Kb : Qb) + (size_t)b * 262144;
        ushort4 st;
        st.x = f2bf((acc[i][j][0] + bias[mb + 0]) * scale);
        st.y = f2bf((acc[i][j][1] + bias[mb + 1]) * scale);
        st.z = f2bf((acc[i][j][2] + bias[mb + 2]) * scale);
        st.w = f2bf((acc[i][j][3] + bias[mb + 3]) * scale);
        // head-packed (h, s, dh); mb%4==0 so the quad stays inside one head
        *(ushort4*)(D + (size_t)(mb >> 5) * 32768 + (size_t)n * 32 + (mb & 31)) = st;
      } else {
        u16* D = Vb + (size_t)b * 262144;
#pragma unroll
        for (int r = 0; r < 4; r++) {
          const int m = mb + r;
          D[(size_t)m * 1024 + n] = f2bf(acc[i][j][r] + bias[m]);
        }
      }
    }
  }
}

// ---------- fused attention v10: 32x32 MFMA, in-register P repack, swizzled dbuf LDS ----------
// Q/K head-packed (b,h,s,32): per-(b,h) contiguous 64KB -> dense reads, FETCH
// at the unique-footprint floor (R3: 44.6MB). VALU-issue-bound now (65%/26%).
__global__ void __launch_bounds__(512) attn_kernel(const u16* __restrict__ Q,
                                                   const u16* __restrict__ K,
                                                   const u16* __restrict__ V,
                                                   u16* __restrict__ O) {
  const int blk = blockIdx.x;
  const int qc = blk >> 8, bh = blk & 255;
  const int b = bh >> 3, h = bh & 7;
  const int tid = threadIdx.x, wave = tid >> 6, lane = tid & 63;
  const int hi = lane >> 5, l32 = lane & 31;
  __shared__ __align__(16) u16 Ksh[2][128 * 32];  // [t][d] granule-swizzled
  __shared__ __align__(16) u16 Vsh[2][32 * 128];  // [d][t] granule col ^= (d&15)
  const u16* Qg = Q + (size_t)b * 262144 + (size_t)h * 32768;  // (b,h,s,32)
  const u16* Kg = K + (size_t)b * 262144 + (size_t)h * 32768;  // (b,h,s,32)
  const u16* Vg = V + (size_t)b * 262144 + (size_t)h * 32768;  // (b,h,dh,s)
  const int qw = qc * 256 + wave * 32;   // this wave's 32 q rows

  // Q frags (B-operand): lane n=l32 holds Q[q=qw+l32][d = ks*16 + hi*8 + j]
  bf16x8 qf[2];
#pragma unroll
  for (int ks = 0; ks < 2; ks++)
    qf[ks] = *(const bf16x8*)(Qg + (size_t)(qw + l32) * 32 + ks * 16 + hi * 8);

  // K staging: this lane's granule Gg; location Gg must hold K[t(Gg)][8*s(Gg)..+7]
  const int Gg = wave * 64 + lane;
  const int th = Gg >> 3;
  const int uu = (Gg & 7) ^ (th & 7);
  const u16* ksrc = Kg + (size_t)(th * 2 + (uu >> 2)) * 32 + (uu & 3) * 8;
  u16* kdst0 = &Ksh[0][Gg * 8];
  u16* kdst1 = &Ksh[1][Gg * 8];
  // V staging: granule tid holds V[d = tid>>4][8*((tid&15)^(d&15)) ..+7]
  const int vd = tid >> 4;
  const u16* vsrc = Vg + (size_t)vd * 1024 + ((tid & 15) ^ (vd & 15)) * 8;
  u16* vdst0 = &Vsh[0][tid * 8];
  u16* vdst1 = &Vsh[1][tid * 8];

  // kf read byte-offsets (A-operand, lane m = t = tt*32+l32, k-half ks): +tt*2048
  const int kkey = (l32 >> 1) & 7;
  const int kb0 = (l32 >> 1) * 128 + (((((l32 & 1) << 2) | 0 | hi) ^ kkey) << 4);
  const int kb1 = (l32 >> 1) * 128 + (((((l32 & 1) << 2) | 2 | hi) ^ kkey) << 4);
  // vf read byte-offsets: l32*256 + ((tg ^ (l32&15))<<4), tg = 4*tt + 2*m + hi
  int vb[4];
#pragma unroll
  for (int tt = 0; tt < 4; tt++) vb[tt] = l32 * 256 + (((l32 & 12) ^ (tt << 2)) << 4);
  const int vm0 = ((l32 & 3) ^ hi) << 4;
  const int vm1 = ((l32 & 3) ^ (2 | hi)) << 4;

  f32x16 oacc;
#pragma unroll
  for (int r = 0; r < 16; r++) oacc[r] = 0.f;
  f32x16 zro;   // persistent zero C-operand for QK^T (never written)
#pragma unroll
  for (int r = 0; r < 16; r++) zro[r] = 0.f;
  float lsum = 0.f;

  // prologue: stage tile 0
  gld16(ksrc, kdst0);
  gld16(vsrc, vdst0);
  __syncthreads();

#pragma unroll 1
  for (int kt = 0; kt < 8; kt++) {
    const int c = kt & 1;
    if (kt < 7) {   // issue next tile into the other buffer; drained at loop-end barrier
      gld16(ksrc + (size_t)(kt + 1) * 4096, c ? kdst0 : kdst1);   // 128 t-rows x 32
      gld16(vsrc + (kt + 1) * 128,          c ? vdst0 : vdst1);
    }
    const char* Kb = (const char*)&Ksh[c][0];
    const char* Vb = (const char*)&Vsh[c][0];
#pragma unroll
    for (int tt = 0; tt < 4; tt++) {
      const bf16x8 kf0 = *(const bf16x8*)(Kb + tt * 2048 + kb0);
      const bf16x8 kf1 = *(const bf16x8*)(Kb + tt * 2048 + kb1);
      const bf16x8 vf0 = *(const bf16x8*)(Vb + vb[tt] + vm0);
      const bf16x8 vf1 = *(const bf16x8*)(Vb + vb[tt] + vm1);
      __builtin_amdgcn_s_setprio(1);
      f32x16 sf = __builtin_amdgcn_mfma_f32_32x32x16_bf16(kf0, qf[0], zro, 0, 0, 0);
      sf = __builtin_amdgcn_mfma_f32_32x32x16_bf16(kf1, qf[1], sf, 0, 0, 0);
      __builtin_amdgcn_s_setprio(0);
      // ---- first 16 t of the tile (groups g0 = sf[0:3], g1 = sf[4:7]) ----
      {
        const float p0 = __builtin_amdgcn_exp2f(sf[0]);
        const float p1 = __builtin_amdgcn_exp2f(sf[1]);
        const float p2 = __builtin_amdgcn_exp2f(sf[2]);
        const float p3 = __builtin_amdgcn_exp2f(sf[3]);
        const float p4 = __builtin_amdgcn_exp2f(sf[4]);
        const float p5 = __builtin_amdgcn_exp2f(sf[5]);
        const float p6 = __builtin_amdgcn_exp2f(sf[6]);
        const float p7 = __builtin_amdgcn_exp2f(sf[7]);
        lsum += ((p0 + p1) + (p2 + p3)) + ((p4 + p5) + (p6 + p7));
        u32 wa, wb, wc, wd;
        asm("v_cvt_pk_bf16_f32 %0, %1, %2" : "=v"(wa) : "v"(p0), "v"(p1));
        asm("v_cvt_pk_bf16_f32 %0, %1, %2" : "=v"(wb) : "v"(p2), "v"(p3));
        asm("v_cvt_pk_bf16_f32 %0, %1, %2" : "=v"(wc) : "v"(p4), "v"(p5));
        asm("v_cvt_pk_bf16_f32 %0, %1, %2" : "=v"(wd) : "v"(p6), "v"(p7));
#if __has_builtin(__builtin_amdgcn_permlane32_swap)
        auto s0 = __builtin_amdgcn_permlane32_swap((int)wc, (int)wa, false, false);
        auto s1 = __builtin_amdgcn_permlane32_swap((int)wd, (int)wb, false, false);
        union { int w[4]; bf16x8 v; } pk;
        pk.w[0] = s0[1]; pk.w[1] = s1[1]; pk.w[2] = s0[0]; pk.w[3] = s1[0];
#else
        const u32 xa = __shfl_xor((int)wa, 32), xb = __shfl_xor((int)wb, 32);
        const u32 xc = __shfl_xor((int)wc, 32), xd = __shfl_xor((int)wd, 32);
        union { u32 w[4]; bf16x8 v; } pk;
        pk.w[0] = hi ? xc : wa; pk.w[1] = hi ? xd : wb;
        pk.w[2] = hi ? wc : xa; pk.w[3] = hi ? wd : xb;
#endif
        __builtin_amdgcn_s_setprio(1);
        oacc = __builtin_amdgcn_mfma_f32_32x32x16_bf16(pk.v, vf0, oacc, 0, 0, 0);
        __builtin_amdgcn_s_setprio(0);
      }
      // ---- second 16 t of the tile (groups g2 = sf[8:11], g3 = sf[12:15]) ----
      {
        const float p0 = __builtin_amdgcn_exp2f(sf[8]);
        const float p1 = __builtin_amdgcn_exp2f(sf[9]);
        const float p2 = __builtin_amdgcn_exp2f(sf[10]);
        const float p3 = __builtin_amdgcn_exp2f(sf[11]);
        const float p4 = __builtin_amdgcn_exp2f(sf[12]);
        const float p5 = __builtin_amdgcn_exp2f(sf[13]);
        const float p6 = __builtin_amdgcn_exp2f(sf[14]);
        const float p7 = __builtin_amdgcn_exp2f(sf[15]);
        lsum += ((p0 + p1) + (p2 + p3)) + ((p4 + p5) + (p6 + p7));
        u32 wa, wb, wc, wd;
        asm("v_cvt_pk_bf16_f32 %0, %1, %2" : "=v"(wa) : "v"(p0), "v"(p1));
        asm("v_cvt_pk_bf16_f32 %0, %1, %2" : "=v"(wb) : "v"(p2), "v"(p3));
        asm("v_cvt_pk_bf16_f32 %0, %1, %2" : "=v"(wc) : "v"(p4), "v"(p5));
        asm("v_cvt_pk_bf16_f32 %0, %1, %2" : "=v"(wd) : "v"(p6), "v"(p7));
#if __has_builtin(__builtin_amdgcn_permlane32_swap)
        auto s0 = __builtin_amdgcn_permlane32_swap((int)wc, (int)wa, false, false);
        auto s1 = __builtin_amdgcn_permlane32_swap((int)wd, (int)wb, false, false);
        union { int w[4]; bf16x8 v; } pk;
        pk.w[0] = s0[1]; pk.w[1] = s1[1]; pk.w[2] = s0[0]; pk.w[3] = s1[0];
#else
        const u32 xa = __shfl_xor((int)wa, 32), xb = __shfl_xor((int)wb, 32);
        const u32 xc = __shfl_xor((int)wc, 32), xd = __shfl_xor((int)wd, 32);
        union { u32 w[4]; bf16x8 v; } pk;
        pk.w[0] = hi ? xc : wa; pk.w[1] = hi ? xd : wb;
        pk.w[2] = hi ? wc : xa; pk.w[3] = hi ? wd : xb;
#endif
        __builtin_amdgcn_s_setprio(1);
        oacc = __builtin_amdgcn_mfma_f32_32x32x16_bf16(pk.v, vf1, oacc, 0, 0, 0);
        __builtin_amdgcn_s_setprio(0);
      }
    }
    if (kt < 7) __syncthreads();   // drains vmcnt (prefetch) + WAR for restage
  }

  // epilogue: row-sums (lane + its hi-partner), scale, store
  lsum += __shfl_xor(lsum, 32);
  const float linv = 1.0f / lsum;            // valid at lane for q = l32
  u16* Og = O + (size_t)(b * 1024 + qw) * 256 + h * 32 + l32;
#pragma unroll
  for (int r = 0; r < 16; r++) {
    const int qo = (r & 3) + 8 * (r >> 2) + 4 * hi;   // oacc row -> q offset
    const float li = __shfl(linv, qo);
    Og[(size_t)qo * 256] = f2bf(oacc[r] * li);
  }
}

// ---------- out projection + residual: out = 2x + g*(Wo.O + bo) ----------
// v3 orientation swap: D[m=s][n=c] so the per-lane register dim (4 consecutive
// s) is contiguous in out(c,s) -> float4 x-loads and float4 stores on the
// 256MB f32 stream (was scalar 4B). Tiles 128(s) x 64(c), grid (8,4,32) = 1024.
__global__ void __launch_bounds__(256) out_gemm(const u16* __restrict__ WoB,
                                                const float* __restrict__ bg,
                                                const u16* __restrict__ Ob,
                                                const void* __restrict__ xin,
                                                void* __restrict__ outp,
                                                const u32* __restrict__ xdet) {
  const int b = blockIdx.z;
  const int m0 = blockIdx.x * 128;   // s tile (8)
  const int n0 = blockIdx.y * 64;    // c tile (4)
  const int tid = threadIdx.x, lane = tid & 63, wave = tid >> 6;
  const int quad = lane >> 4, l16 = lane & 15;
  const int wm = wave >> 1, wn = wave & 1;   // per wave: 64 m x 32 n
  const int isbf = detect_bf16(xdet);
  const u16* Ab = Ob + (size_t)b * 262144;   // A rows = s (k-major 256)
  __shared__ u16 Ash[8192], Bsh[4096];       // A 128x64, B 64x64 (swizzled granules)
  f32x4 acc[4][2];
#pragma unroll
  for (int i = 0; i < 4; i++)
#pragma unroll
    for (int j = 0; j < 2; j++) acc[i][j] = (f32x4){0.f, 0.f, 0.f, 0.f};

  const int srow = lane >> 3;
  const int sgc = (lane & 7) ^ (srow & 7);   // pre-swizzled source k-granule
  for (int k0 = 0; k0 < 256; k0 += 64) {
    __syncthreads();
#pragma unroll
    for (int p = 0; p < 4; p++) {
      const int row = p * 32 + wave * 8;
      gld16(Ab + (size_t)(m0 + row + srow) * 256 + k0 + sgc * 8, &Ash[row * 64 + lane * 8]);
    }
#pragma unroll
    for (int p = 0; p < 2; p++) {
      const int row = p * 32 + wave * 8;
      gld16(WoB + (size_t)(n0 + row + srow) * 256 + k0 + sgc * 8, &Bsh[row * 64 + lane * 8]);
    }
    __syncthreads();
#pragma unroll
    for (int kk = 0; kk < 2; kk++) {
      bf16x8 av[4], bv[2];
      const int rg = (kk * 4 + quad) ^ (l16 & 7);   // swizzled read granule
#pragma unroll
      for (int i = 0; i < 4; i++) av[i] = *(const bf16x8*)&Ash[(wm * 64 + i * 16 + l16) * 64 + rg * 8];
#pragma unroll
      for (int j = 0; j < 2; j++) bv[j] = *(const bf16x8*)&Bsh[(wn * 32 + j * 16 + l16) * 64 + rg * 8];
#pragma unroll
      for (int i = 0; i < 4; i++)
#pragma unroll
        for (int j = 0; j < 2; j++)
          acc[i][j] = __builtin_amdgcn_mfma_f32_16x16x32_bf16(av[i], bv[j], acc[i][j], 0, 0, 0);
    }
  }

  const float g = bg[256];
#pragma unroll
  for (int i = 0; i < 4; i++) {
#pragma unroll
    for (int j = 0; j < 2; j++) {
      const int mb = m0 + wm * 64 + i * 16 + quad * 4;   // s, 4-consecutive via r
      const int n = n0 + wn * 32 + j * 16 + l16;         // c
      const float bc = bg[n];
      const size_t gi = (size_t)b * 262144 + (size_t)n * 1024 + mb;
      if (isbf) {
        const ushort4 xv = *(const ushort4*)((const u16*)xin + gi);
        ushort4 st;
        st.x = f2bf(2.f * bf2f(xv.x) + g * (acc[i][j][0] + bc));
        st.y = f2bf(2.f * bf2f(xv.y) + g * (acc[i][j][1] + bc));
        st.z = f2bf(2.f * bf2f(xv.z) + g * (acc[i][j][2] + bc));
        st.w = f2bf(2.f * bf2f(xv.w) + g * (acc[i][j][3] + bc));
        *(ushort4*)((u16*)outp + gi) = st;
      } else {
        const float4 xv = *(const float4*)((const float*)xin + gi);
        float4 st;
        st.x = 2.f * xv.x + g * (acc[i][j][0] + bc);
        st.y = 2.f * xv.y + g * (acc[i][j][1] + bc);
        st.z = 2.f * xv.z + g * (acc[i][j][2] + bc);
        st.w = 2.f * xv.w + g * (acc[i][j][3] + bc);
        *(float4*)((float*)outp + gi) = st;
      }
    }
  }
}

// ---------- launcher ----------
extern "C" void kernel_launch(void* const* d_in, const int* in_sizes, int n_in,
                              void* d_out, int out_size, void* d_ws, size_t ws_size,
                              hipStream_t stream) {
  const void* x  = d_in[0];
  const void* Wq = d_in[1]; const void* bq = d_in[2];
  const void* Wk = d_in[3]; const void* bk = d_in[4];
  const void* Wv = d_in[5]; const void* bv = d_in[6];
  const void* Wo = d_in[7]; const void* bo = d_in[8];
  const void* gm = d_in[9];

  u16* ws = (u16*)d_ws;
  u16* xT = ws;            // (b,s,c) bf16; reused as O after V-proj
  u16* Qb = ws + NT;       // (b,h,s,32), scale*log2e folded
  u16* Kb = ws + 2 * NT;   // (b,h,s,32)
  u16* Vb = ws + 3 * NT;   // (b,256,s) == (b,h,dh,s)
  u16* Ob = xT;
  const u32* xdet = (const u32*)x;

  // d_out doubles as QKV-weight scratch until out_gemm rewrites it fully
  u16* WqkvB = (u16*)d_out;                              // 3 x 65536 u16
  float* bqkvF = (float*)((u16*)d_out + 196608);         // 768 f32

  // Wo scratch: ws tail if it fits (prep folded into prologue), else dead-Q fallback
  const bool tail = ws_size >= (size_t)(4 * NT + 66048) * 2;
  u16* WoB = tail ? (ws + 4 * NT) : Qb;
  float* boF = tail ? (float*)(ws + 4 * NT + 65536) : (float*)(Qb + 65536);

  prologue_kernel<<<dim3(tail ? 2304 : 2240), 256, 0, stream>>>(
      x, xT, Wq, Wk, Wv, bq, bk, bv, WqkvB, bqkvF, Wo, bo, gm, WoB, boF);
  qkv_gemm<<<dim3(8, 2, 96), 256, 0, stream>>>(xT, WqkvB, bqkvF, Qb, Kb, Vb);
  attn_kernel<<<dim3(1024), 512, 0, stream>>>(Qb, Kb, Vb, Ob);
  if (!tail) prep_o<<<dim3(64), 256, 0, stream>>>(Wo, bo, gm, WoB, boF, xdet);
  out_gemm<<<dim3(8, 4, 32), 256, 0, stream>>>(WoB, boF, Ob, x, d_out, xdet);
}

// Round 5
// 188.585 us; speedup vs baseline: 1.1067x; 1.0006x over previous
//
#include <hip/hip_runtime.h>
#include <stdint.h>

typedef unsigned short u16;
typedef unsigned int   u32;
typedef __attribute__((ext_vector_type(8))) short bf16x8;  // 8 bf16 = 4 VGPR
typedef __attribute__((ext_vector_type(4))) short bf16x4;  // 4 bf16 = 2 VGPR
typedef __attribute__((ext_vector_type(4))) float f32x4;   // MFMA C/D frag
typedef __attribute__((ext_vector_type(16))) float f32x16; // 32x32 MFMA C/D frag

#define NT ((size_t)8388608)   // 32*1024*256 elements

// ---------- helpers ----------
__device__ __forceinline__ float bf2f(u16 u) {
  union { float f; u32 i; } v; v.i = ((u32)u) << 16; return v.f;
}
__device__ __forceinline__ u16 f2bf(float f) {
  union { float f; u32 i; } v; v.f = f;
  u32 r = (v.i + 0x7fffu + ((v.i >> 16) & 1u)) >> 16;   // RNE
  return (u16)r;
}
__device__ __forceinline__ u32 fbits(float f) {
  union { float f; u32 i; } v; v.f = f; return v.i;
}
// bf16-vs-f32 buffer sniff (64-lane ballot on exponent-byte position)
__device__ __forceinline__ int detect_bf16(const u32* __restrict__ xd) {
  u32 w = xd[threadIdx.x & 63];
  u32 e = (w >> 8) & 0x7fu;
  unsigned long long m = __ballot((e >= 0x38u) && (e <= 0x41u));
  return __popcll(m) > 32;
}
// async 16B/lane global->LDS (dest = wave-uniform base + lane*16)
__device__ __forceinline__ void gld16(const void* g, void* l) {
  __builtin_amdgcn_global_load_lds((const __attribute__((address_space(1))) u32*)g,
                                   (__attribute__((address_space(3))) u32*)l, 16, 0, 0);
}

// ---------- prologue: x transpose (0..2047) + Wq/Wk/Wv prep (2048..2239) + optional Wo (2240..2303) ----------
__global__ void __launch_bounds__(256) prologue_kernel(const void* __restrict__ xin,
                                                       u16* __restrict__ xT,
                                                       const void* __restrict__ W0, const void* __restrict__ W1,
                                                       const void* __restrict__ W2, const void* __restrict__ b0,
                                                       const void* __restrict__ b1, const void* __restrict__ b2,
                                                       u16* __restrict__ wdst, float* __restrict__ bdst,
                                                       const void* __restrict__ Wo, const void* __restrict__ bo,
                                                       const void* __restrict__ gm, u16* __restrict__ wodst,
                                                       float* __restrict__ bodst) {
  const int blk = blockIdx.x;
  const int tid = threadIdx.x;
  const int isbf = detect_bf16((const u32*)xin);
  if (blk < 2048) {
    const int s0 = (blk & 15) * 64, c0 = ((blk >> 4) & 3) * 64, b = blk >> 6;
    __shared__ u16 T[64][72];  // [c-local][s-local], +8 pad
    if (isbf) {
      const u16* xp = (const u16*)xin;
      for (int t = tid; t < 512; t += 256) {
        int r = t >> 3, off = (t & 7) * 8;
        *(uint4*)&T[r][off] = *(const uint4*)(xp + ((size_t)(b * 256 + c0 + r)) * 1024 + s0 + off);
      }
    } else {
      const float* xp = (const float*)xin;
      for (int t = tid; t < 512; t += 256) {
        int r = t >> 3, off = (t & 7) * 8;
        const float* s = xp + ((size_t)(b * 256 + c0 + r)) * 1024 + s0 + off;
#pragma unroll
        for (int u = 0; u < 8; u++) T[r][off + u] = f2bf(s[u]);
      }
    }
    __syncthreads();
    for (int t = tid; t < 512; t += 256) {
      int r = t >> 3, off = (t & 7) * 8;   // r = s-local, off = c-local
      union { u16 h[8]; uint4 v; } pk;
#pragma unroll
      for (int u = 0; u < 8; u++) pk.h[u] = T[off + u][r];
      *(uint4*)(xT + ((size_t)(b * 1024 + s0 + r)) * 256 + c0 + off) = pk.v;
    }
  } else if (blk < 2240) {
    const int g = blk - 2048;            // 192 blocks: 64 per weight
    const int which = g >> 6, bk = g & 63;
    const void* Ws = which == 0 ? W0 : which == 1 ? W1 : W2;
    const void* bs = which == 0 ? b0 : which == 1 ? b1 : b2;
    const int idx = bk * 1024 + tid * 4;
    u16* dst = wdst + which * 65536 + idx;
    if (isbf) {
      *(ushort4*)dst = *(const ushort4*)((const u16*)Ws + idx);
    } else {
      const float* s = (const float*)Ws + idx;
      ushort4 o; o.x = f2bf(s[0]); o.y = f2bf(s[1]); o.z = f2bf(s[2]); o.w = f2bf(s[3]);
      *(ushort4*)dst = o;
    }
    if (bk == 0) {
      bdst[which * 256 + tid] = isbf ? bf2f(((const u16*)bs)[tid]) : ((const float*)bs)[tid];
    }
  } else {
    const int g = blk - 2240;            // 64 blocks: Wo
    const int idx = g * 1024 + tid * 4;
    if (isbf) {
      *(ushort4*)(wodst + idx) = *(const ushort4*)((const u16*)Wo + idx);
    } else {
      const float* s = (const float*)Wo + idx;
      ushort4 o; o.x = f2bf(s[0]); o.y = f2bf(s[1]); o.z = f2bf(s[2]); o.w = f2bf(s[3]);
      *(ushort4*)(wodst + idx) = o;
    }
    if (g == 0) {
      bodst[tid] = isbf ? bf2f(((const u16*)bo)[tid]) : ((const float*)bo)[tid];
      if (tid == 0) bodst[256] = isbf ? bf2f(((const u16*)gm)[0]) : ((const float*)gm)[0];
    }
  }
}

// ---------- Wo prep fallback (when ws tail unavailable; runs after attn) ----------
__global__ void __launch_bounds__(256) prep_o(const void* __restrict__ Wo, const void* __restrict__ bo,
                                              const void* __restrict__ gm, u16* __restrict__ wdst,
                                              float* __restrict__ bdst, const u32* __restrict__ xdet) {
  const int isbf = detect_bf16(xdet);
  const int idx = blockIdx.x * 1024 + threadIdx.x * 4;
  if (isbf) {
    *(ushort4*)(wdst + idx) = *(const ushort4*)((const u16*)Wo + idx);
  } else {
    const float* s = (const float*)Wo + idx;
    ushort4 o; o.x = f2bf(s[0]); o.y = f2bf(s[1]); o.z = f2bf(s[2]); o.w = f2bf(s[3]);
    *(ushort4*)(wdst + idx) = o;
  }
  if (blockIdx.x == 0) {
    int t = threadIdx.x;
    bdst[t] = isbf ? bf2f(((const u16*)bo)[t]) : ((const float*)bo)[t];
    if (t == 0) bdst[256] = isbf ? bf2f(((const u16*)gm)[0]) : ((const float*)gm)[0];
  }
}

// ---------- fused QKV projection, BK=64, unified orientation: D[m=c][n=s] ----------
// A = W (rows c), B = xT (rows s) for ALL three projections. The register dim
// (quad*4+r) is now c -> for Q/K head-packed (b,h,s,32) the 4 consecutive dh
// form one contiguous ushort4 store (was 4 scalar u16 at 64B stride).
// V store (b,c,s) unchanged-scalar (n=s is the lane dim there).
__global__ void __launch_bounds__(256) qkv_gemm(const u16* __restrict__ xT,
                                                const u16* __restrict__ Wall,
                                                const float* __restrict__ ball,
                                                u16* __restrict__ Qb, u16* __restrict__ Kb,
                                                u16* __restrict__ Vb) {
  const int z = blockIdx.z, b = z / 3, which = z - b * 3;
  const int tid = threadIdx.x, lane = tid & 63, wave = tid >> 6;
  const int quad = lane >> 4, l16 = lane & 15;
  const int wm = wave >> 1, wn = wave & 1;
  const u16* xb = xT + (size_t)b * 262144;
  const u16* W = Wall + which * 65536;
  const int m0 = blockIdx.y * 128;   // c tile (2)
  const int n0 = blockIdx.x * 128;   // s tile (8)

  __shared__ u16 Ash[8192], Bsh[8192];   // 128 rows x 64 (128B rows), k-granule swizzled
  f32x4 acc[4][4];
#pragma unroll
  for (int i = 0; i < 4; i++)
#pragma unroll
    for (int j = 0; j < 4; j++) acc[i][j] = (f32x4){0.f, 0.f, 0.f, 0.f};

  const int srow = lane >> 3;
  const int sgc = (lane & 7) ^ (srow & 7);   // pre-swizzled source k-granule
  for (int k0 = 0; k0 < 256; k0 += 64) {
    __syncthreads();   // WAR: prior frag reads done before restage lands
#pragma unroll
    for (int p = 0; p < 4; p++) {
      const int row = p * 32 + wave * 8;
      gld16(W  + (size_t)(m0 + row + srow) * 256 + k0 + sgc * 8, &Ash[row * 64 + lane * 8]);
      gld16(xb + (size_t)(n0 + row + srow) * 256 + k0 + sgc * 8, &Bsh[row * 64 + lane * 8]);
    }
    __syncthreads();   // drains vmcnt before barrier
#pragma unroll
    for (int kk = 0; kk < 2; kk++) {
      bf16x8 av[4], bv[4];
      const int rg = (kk * 4 + quad) ^ (l16 & 7);   // swizzled read granule
#pragma unroll
      for (int i = 0; i < 4; i++) av[i] = *(const bf16x8*)&Ash[(wm * 64 + i * 16 + l16) * 64 + rg * 8];
#pragma unroll
      for (int j = 0; j < 4; j++) bv[j] = *(const bf16x8*)&Bsh[(wn * 64 + j * 16 + l16) * 64 + rg * 8];
#pragma unroll
      for (int i = 0; i < 4; i++)
#pragma unroll
        for (int j = 0; j < 4; j++)
          acc[i][j] = __builtin_amdgcn_mfma_f32_16x16x32_bf16(av[i], bv[j], acc[i][j], 0, 0, 0);
    }
  }

  const float* bias = ball + which * 256;
  const float scale = (which == 0) ? 0.25503486f : 1.0f;  // (1/sqrt(32))*log2(e) folded into Q
#pragma unroll
  for (int i = 0; i < 4; i++) {
#pragma unroll
    for (int j = 0; j < 4; j++) {
      const int mb = m0 + wm * 64 + i * 16 + quad * 4;   // c, 4-consecutive via r
      const int n = n0 + wn * 64 + j * 16 + l16;         // s
      if (which < 2) {
        u16* D = (which ? Kb : Qb) + (size_t)b * 262144;
        ushort4 st;
        st.x = f2bf((acc[i][j][0] + bias[mb + 0]) * scale);
        st.y = f2bf((acc[i][j][1] + bias[mb + 1]) * scale);
        st.z = f2bf((acc[i][j][2] + bias[mb + 2]) * scale);
        st.w = f2bf((acc[i][j][3] + bias[mb + 3]) * scale);
        // head-packed (h, s, dh); mb%4==0 so the quad stays inside one head
        *(ushort4*)(D + (size_t)(mb >> 5) * 32768 + (size_t)n * 32 + (mb & 31)) = st;
      } else {
        u16* D = Vb + (size_t)b * 262144;
#pragma unroll
        for (int r = 0; r < 4; r++) {
          const int m = mb + r;
          D[(size_t)m * 1024 + n] = f2bf(acc[i][j][r] + bias[m]);
        }
      }
    }
  }
}

// ---------- fused attention v11: rolled tt loop for occupancy ----------
// R4 counters: OccupancyPercent 33% (~2.6 waves/SIMD) -- register-limited.
// The unrolled tt loop hoisted all 16 ds_read frags (64 VGPRs in flight).
// Rolling it (#pragma unroll 1, vbt computed inline to avoid rule-#20
// runtime-indexed-array scratch) cuts live frags 64 -> 16, targeting
// ~128 total regs = 4 waves/SIMD; the extra waves hide the per-iter
// ds_read latency the unroll was hiding statically.
__global__ void __launch_bounds__(512) attn_kernel(const u16* __restrict__ Q,
                                                   const u16* __restrict__ K,
                                                   const u16* __restrict__ V,
                                                   u16* __restrict__ O) {
  const int blk = blockIdx.x;
  const int qc = blk >> 8, bh = blk & 255;
  const int b = bh >> 3, h = bh & 7;
  const int tid = threadIdx.x, wave = tid >> 6, lane = tid & 63;
  const int hi = lane >> 5, l32 = lane & 31;
  __shared__ __align__(16) u16 Ksh[2][128 * 32];  // [t][d] granule-swizzled
  __shared__ __align__(16) u16 Vsh[2][32 * 128];  // [d][t] granule col ^= (d&15)
  const u16* Qg = Q + (size_t)b * 262144 + (size_t)h * 32768;  // (b,h,s,32)
  const u16* Kg = K + (size_t)b * 262144 + (size_t)h * 32768;  // (b,h,s,32)
  const u16* Vg = V + (size_t)b * 262144 + (size_t)h * 32768;  // (b,h,dh,s)
  const int qw = qc * 256 + wave * 32;   // this wave's 32 q rows

  // Q frags (B-operand): lane n=l32 holds Q[q=qw+l32][d = ks*16 + hi*8 + j]
  bf16x8 qf[2];
#pragma unroll
  for (int ks = 0; ks < 2; ks++)
    qf[ks] = *(const bf16x8*)(Qg + (size_t)(qw + l32) * 32 + ks * 16 + hi * 8);

  // K staging: this lane's granule Gg; location Gg must hold K[t(Gg)][8*s(Gg)..+7]
  const int Gg = wave * 64 + lane;
  const int th = Gg >> 3;
  const int uu = (Gg & 7) ^ (th & 7);
  const u16* ksrc = Kg + (size_t)(th * 2 + (uu >> 2)) * 32 + (uu & 3) * 8;
  u16* kdst0 = &Ksh[0][Gg * 8];
  u16* kdst1 = &Ksh[1][Gg * 8];
  // V staging: granule tid holds V[d = tid>>4][8*((tid&15)^(d&15)) ..+7]
  const int vd = tid >> 4;
  const u16* vsrc = Vg + (size_t)vd * 1024 + ((tid & 15) ^ (vd & 15)) * 8;
  u16* vdst0 = &Vsh[0][tid * 8];
  u16* vdst1 = &Vsh[1][tid * 8];

  // kf read byte-offsets (A-operand, lane m = t = tt*32+l32, k-half ks): +tt*2048
  const int kkey = (l32 >> 1) & 7;
  const int kb0 = (l32 >> 1) * 128 + (((((l32 & 1) << 2) | 0 | hi) ^ kkey) << 4);
  const int kb1 = (l32 >> 1) * 128 + (((((l32 & 1) << 2) | 2 | hi) ^ kkey) << 4);
  // vf read byte-offsets computed inline per tt (rolled loop; no runtime-indexed array)
  const int vm0 = ((l32 & 3) ^ hi) << 4;
  const int vm1 = ((l32 & 3) ^ (2 | hi)) << 4;

  f32x16 oacc;
#pragma unroll
  for (int r = 0; r < 16; r++) oacc[r] = 0.f;
  f32x16 zro;   // persistent zero C-operand for QK^T (never written)
#pragma unroll
  for (int r = 0; r < 16; r++) zro[r] = 0.f;
  float lsum = 0.f;

  // prologue: stage tile 0
  gld16(ksrc, kdst0);
  gld16(vsrc, vdst0);
  __syncthreads();

#pragma unroll 1
  for (int kt = 0; kt < 8; kt++) {
    const int c = kt & 1;
    if (kt < 7) {   // issue next tile into the other buffer; drained at loop-end barrier
      gld16(ksrc + (size_t)(kt + 1) * 4096, c ? kdst0 : kdst1);   // 128 t-rows x 32
      gld16(vsrc + (kt + 1) * 128,          c ? vdst0 : vdst1);
    }
    const char* Kb = (const char*)&Ksh[c][0];
    const char* Vb = (const char*)&Vsh[c][0];
#pragma unroll 1
    for (int tt = 0; tt < 4; tt++) {
      const int vbt = l32 * 256 + (((l32 & 12) ^ (tt << 2)) << 4);
      const bf16x8 kf0 = *(const bf16x8*)(Kb + tt * 2048 + kb0);
      const bf16x8 kf1 = *(const bf16x8*)(Kb + tt * 2048 + kb1);
      const bf16x8 vf0 = *(const bf16x8*)(Vb + vbt + vm0);
      const bf16x8 vf1 = *(const bf16x8*)(Vb + vbt + vm1);
      __builtin_amdgcn_s_setprio(1);
      f32x16 sf = __builtin_amdgcn_mfma_f32_32x32x16_bf16(kf0, qf[0], zro, 0, 0, 0);
      sf = __builtin_amdgcn_mfma_f32_32x32x16_bf16(kf1, qf[1], sf, 0, 0, 0);
      __builtin_amdgcn_s_setprio(0);
      // ---- first 16 t of the tile (groups g0 = sf[0:3], g1 = sf[4:7]) ----
      {
        const float p0 = __builtin_amdgcn_exp2f(sf[0]);
        const float p1 = __builtin_amdgcn_exp2f(sf[1]);
        const float p2 = __builtin_amdgcn_exp2f(sf[2]);
        const float p3 = __builtin_amdgcn_exp2f(sf[3]);
        const float p4 = __builtin_amdgcn_exp2f(sf[4]);
        const float p5 = __builtin_amdgcn_exp2f(sf[5]);
        const float p6 = __builtin_amdgcn_exp2f(sf[6]);
        const float p7 = __builtin_amdgcn_exp2f(sf[7]);
        lsum += ((p0 + p1) + (p2 + p3)) + ((p4 + p5) + (p6 + p7));
        u32 wa, wb, wc, wd;
        asm("v_cvt_pk_bf16_f32 %0, %1, %2" : "=v"(wa) : "v"(p0), "v"(p1));
        asm("v_cvt_pk_bf16_f32 %0, %1, %2" : "=v"(wb) : "v"(p2), "v"(p3));
        asm("v_cvt_pk_bf16_f32 %0, %1, %2" : "=v"(wc) : "v"(p4), "v"(p5));
        asm("v_cvt_pk_bf16_f32 %0, %1, %2" : "=v"(wd) : "v"(p6), "v"(p7));
#if __has_builtin(__builtin_amdgcn_permlane32_swap)
        auto s0 = __builtin_amdgcn_permlane32_swap((int)wc, (int)wa, false, false);
        auto s1 = __builtin_amdgcn_permlane32_swap((int)wd, (int)wb, false, false);
        union { int w[4]; bf16x8 v; } pk;
        pk.w[0] = s0[1]; pk.w[1] = s1[1]; pk.w[2] = s0[0]; pk.w[3] = s1[0];
#else
        const u32 xa = __shfl_xor((int)wa, 32), xb = __shfl_xor((int)wb, 32);
        const u32 xc = __shfl_xor((int)wc, 32), xd = __shfl_xor((int)wd, 32);
        union { u32 w[4]; bf16x8 v; } pk;
        pk.w[0] = hi ? xc : wa; pk.w[1] = hi ? xd : wb;
        pk.w[2] = hi ? wc : xa; pk.w[3] = hi ? wd : xb;
#endif
        __builtin_amdgcn_s_setprio(1);
        oacc = __builtin_amdgcn_mfma_f32_32x32x16_bf16(pk.v, vf0, oacc, 0, 0, 0);
        __builtin_amdgcn_s_setprio(0);
      }
      // ---- second 16 t of the tile (groups g2 = sf[8:11], g3 = sf[12:15]) ----
      {
        const float p0 = __builtin_amdgcn_exp2f(sf[8]);
        const float p1 = __builtin_amdgcn_exp2f(sf[9]);
        const float p2 = __builtin_amdgcn_exp2f(sf[10]);
        const float p3 = __builtin_amdgcn_exp2f(sf[11]);
        const float p4 = __builtin_amdgcn_exp2f(sf[12]);
        const float p5 = __builtin_amdgcn_exp2f(sf[13]);
        const float p6 = __builtin_amdgcn_exp2f(sf[14]);
        const float p7 = __builtin_amdgcn_exp2f(sf[15]);
        lsum += ((p0 + p1) + (p2 + p3)) + ((p4 + p5) + (p6 + p7));
        u32 wa, wb, wc, wd;
        asm("v_cvt_pk_bf16_f32 %0, %1, %2" : "=v"(wa) : "v"(p0), "v"(p1));
        asm("v_cvt_pk_bf16_f32 %0, %1, %2" : "=v"(wb) : "v"(p2), "v"(p3));
        asm("v_cvt_pk_bf16_f32 %0, %1, %2" : "=v"(wc) : "v"(p4), "v"(p5));
        asm("v_cvt_pk_bf16_f32 %0, %1, %2" : "=v"(wd) : "v"(p6), "v"(p7));
#if __has_builtin(__builtin_amdgcn_permlane32_swap)
        auto s0 = __builtin_amdgcn_permlane32_swap((int)wc, (int)wa, false, false);
        auto s1 = __builtin_amdgcn_permlane32_swap((int)wd, (int)wb, false, false);
        union { int w[4]; bf16x8 v; } pk;
        pk.w[0] = s0[1]; pk.w[1] = s1[1]; pk.w[2] = s0[0]; pk.w[3] = s1[0];
#else
        const u32 xa = __shfl_xor((int)wa, 32), xb = __shfl_xor((int)wb, 32);
        const u32 xc = __shfl_xor((int)wc, 32), xd = __shfl_xor((int)wd, 32);
        union { u32 w[4]; bf16x8 v; } pk;
        pk.w[0] = hi ? xc : wa; pk.w[1] = hi ? xd : wb;
        pk.w[2] = hi ? wc : xa; pk.w[3] = hi ? wd : xb;
#endif
        __builtin_amdgcn_s_setprio(1);
        oacc = __builtin_amdgcn_mfma_f32_32x32x16_bf16(pk.v, vf1, oacc, 0, 0, 0);
        __builtin_amdgcn_s_setprio(0);
      }
    }
    if (kt < 7) __syncthreads();   // drains vmcnt (prefetch) + WAR for restage
  }

  // epilogue: row-sums (lane + its hi-partner), scale, store
  lsum += __shfl_xor(lsum, 32);
  const float linv = 1.0f / lsum;            // valid at lane for q = l32
  u16* Og = O + (size_t)(b * 1024 + qw) * 256 + h * 32 + l32;
#pragma unroll
  for (int r = 0; r < 16; r++) {
    const int qo = (r & 3) + 8 * (r >> 2) + 4 * hi;   // oacc row -> q offset
    const float li = __shfl(linv, qo);
    Og[(size_t)qo * 256] = f2bf(oacc[r] * li);
  }
}

// ---------- out projection + residual: out = 2x + g*(Wo.O + bo) ----------
// Orientation: D[m=s][n=c] so the per-lane register dim (4 consecutive s) is
// contiguous in out(c,s) -> float4 x-loads and float4 stores on the 256MB f32
// stream. Tiles 128(s) x 64(c), grid (8,4,32) = 1024.
__global__ void __launch_bounds__(256) out_gemm(const u16* __restrict__ WoB,
                                                const float* __restrict__ bg,
                                                const u16* __restrict__ Ob,
                                                const void* __restrict__ xin,
                                                void* __restrict__ outp,
                                                const u32* __restrict__ xdet) {
  const int b = blockIdx.z;
  const int m0 = blockIdx.x * 128;   // s tile (8)
  const int n0 = blockIdx.y * 64;    // c tile (4)
  const int tid = threadIdx.x, lane = tid & 63, wave = tid >> 6;
  const int quad = lane >> 4, l16 = lane & 15;
  const int wm = wave >> 1, wn = wave & 1;   // per wave: 64 m x 32 n
  const int isbf = detect_bf16(xdet);
  const u16* Ab = Ob + (size_t)b * 262144;   // A rows = s (k-major 256)
  __shared__ u16 Ash[8192], Bsh[4096];       // A 128x64, B 64x64 (swizzled granules)
  f32x4 acc[4][2];
#pragma unroll
  for (int i = 0; i < 4; i++)
#pragma unroll
    for (int j = 0; j < 2; j++) acc[i][j] = (f32x4){0.f, 0.f, 0.f, 0.f};

  const int srow = lane >> 3;
  const int sgc = (lane & 7) ^ (srow & 7);   // pre-swizzled source k-granule
  for (int k0 = 0; k0 < 256; k0 += 64) {
    __syncthreads();
#pragma unroll
    for (int p = 0; p < 4; p++) {
      const int row = p * 32 + wave * 8;
      gld16(Ab + (size_t)(m0 + row + srow) * 256 + k0 + sgc * 8, &Ash[row * 64 + lane * 8]);
    }
#pragma unroll
    for (int p = 0; p < 2; p++) {
      const int row = p * 32 + wave * 8;
      gld16(WoB + (size_t)(n0 + row + srow) * 256 + k0 + sgc * 8, &Bsh[row * 64 + lane * 8]);
    }
    __syncthreads();
#pragma unroll
    for (int kk = 0; kk < 2; kk++) {
      bf16x8 av[4], bv[2];
      const int rg = (kk * 4 + quad) ^ (l16 & 7);   // swizzled read granule
#pragma unroll
      for (int i = 0; i < 4; i++) av[i] = *(const bf16x8*)&Ash[(wm * 64 + i * 16 + l16) * 64 + rg * 8];
#pragma unroll
      for (int j = 0; j < 2; j++) bv[j] = *(const bf16x8*)&Bsh[(wn * 32 + j * 16 + l16) * 64 + rg * 8];
#pragma unroll
      for (int i = 0; i < 4; i++)
#pragma unroll
        for (int j = 0; j < 2; j++)
          acc[i][j] = __builtin_amdgcn_mfma_f32_16x16x32_bf16(av[i], bv[j], acc[i][j], 0, 0, 0);
    }
  }

  const float g = bg[256];
#pragma unroll
  for (int i = 0; i < 4; i++) {
#pragma unroll
    for (int j = 0; j < 2; j++) {
      const int mb = m0 + wm * 64 + i * 16 + quad * 4;   // s, 4-consecutive via r
      const int n = n0 + wn * 32 + j * 16 + l16;         // c
      const float bc = bg[n];
      const size_t gi = (size_t)b * 262144 + (size_t)n * 1024 + mb;
      if (isbf) {
        const ushort4 xv = *(const ushort4*)((const u16*)xin + gi);
        ushort4 st;
        st.x = f2bf(2.f * bf2f(xv.x) + g * (acc[i][j][0] + bc));
        st.y = f2bf(2.f * bf2f(xv.y) + g * (acc[i][j][1] + bc));
        st.z = f2bf(2.f * bf2f(xv.z) + g * (acc[i][j][2] + bc));
        st.w = f2bf(2.f * bf2f(xv.w) + g * (acc[i][j][3] + bc));
        *(ushort4*)((u16*)outp + gi) = st;
      } else {
        const float4 xv = *(const float4*)((const float*)xin + gi);
        float4 st;
        st.x = 2.f * xv.x + g * (acc[i][j][0] + bc);
        st.y = 2.f * xv.y + g * (acc[i][j][1] + bc);
        st.z = 2.f * xv.z + g * (acc[i][j][2] + bc);
        st.w = 2.f * xv.w + g * (acc[i][j][3] + bc);
        *(float4*)((float*)outp + gi) = st;
      }
    }
  }
}

// ---------- launcher ----------
extern "C" void kernel_launch(void* const* d_in, const int* in_sizes, int n_in,
                              void* d_out, int out_size, void* d_ws, size_t ws_size,
                              hipStream_t stream) {
  const void* x  = d_in[0];
  const void* Wq = d_in[1]; const void* bq = d_in[2];
  const void* Wk = d_in[3]; const void* bk = d_in[4];
  const void* Wv = d_in[5]; const void* bv = d_in[6];
  const void* Wo = d_in[7]; const void* bo = d_in[8];
  const void* gm = d_in[9];

  u16* ws = (u16*)d_ws;
  u16* xT = ws;            // (b,s,c) bf16; reused as O after V-proj
  u16* Qb = ws + NT;       // (b,h,s,32), scale*log2e folded
  u16* Kb = ws + 2 * NT;   // (b,h,s,32)
  u16* Vb = ws + 3 * NT;   // (b,256,s) == (b,h,dh,s)
  u16* Ob = xT;
  const u32* xdet = (const u32*)x;

  // d_out doubles as QKV-weight scratch until out_gemm rewrites it fully
  u16* WqkvB = (u16*)d_out;                              // 3 x 65536 u16
  float* bqkvF = (float*)((u16*)d_out + 196608);         // 768 f32

  // Wo scratch: ws tail if it fits (prep folded into prologue), else dead-Q fallback
  const bool tail = ws_size >= (size_t)(4 * NT + 66048) * 2;
  u16* WoB = tail ? (ws + 4 * NT) : Qb;
  float* boF = tail ? (float*)(ws + 4 * NT + 65536) : (float*)(Qb + 65536);

  prologue_kernel<<<dim3(tail ? 2304 : 2240), 256, 0, stream>>>(
      x, xT, Wq, Wk, Wv, bq, bk, bv, WqkvB, bqkvF, Wo, bo, gm, WoB, boF);
  qkv_gemm<<<dim3(8, 2, 96), 256, 0, stream>>>(xT, WqkvB, bqkvF, Qb, Kb, Vb);
  attn_kernel<<<dim3(1024), 512, 0, stream>>>(Qb, Kb, Vb, Ob);
  if (!tail) prep_o<<<dim3(64), 256, 0, stream>>>(Wo, bo, gm, WoB, boF, xdet);
  out_gemm<<<dim3(8, 4, 32), 256, 0, stream>>>(WoB, boF, Ob, x, d_out, xdet);
}

// Round 6
// 187.090 us; speedup vs baseline: 1.1155x; 1.0080x over previous
//
#include <hip/hip_runtime.h>
#include <stdint.h>

typedef unsigned short u16;
typedef unsigned int   u32;
typedef __attribute__((ext_vector_type(8))) short bf16x8;  // 8 bf16 = 4 VGPR
typedef __attribute__((ext_vector_type(4))) short bf16x4;  // 4 bf16 = 2 VGPR
typedef __attribute__((ext_vector_type(4))) float f32x4;   // MFMA C/D frag
typedef __attribute__((ext_vector_type(16))) float f32x16; // 32x32 MFMA C/D frag

#define NT ((size_t)8388608)   // 32*1024*256 elements

// ---------- helpers ----------
__device__ __forceinline__ float bf2f(u16 u) {
  union { float f; u32 i; } v; v.i = ((u32)u) << 16; return v.f;
}
__device__ __forceinline__ u16 f2bf(float f) {
  union { float f; u32 i; } v; v.f = f;
  u32 r = (v.i + 0x7fffu + ((v.i >> 16) & 1u)) >> 16;   // RNE
  return (u16)r;
}
__device__ __forceinline__ u32 fbits(float f) {
  union { float f; u32 i; } v; v.f = f; return v.i;
}
// bf16-vs-f32 buffer sniff (64-lane ballot on exponent-byte position)
__device__ __forceinline__ int detect_bf16(const u32* __restrict__ xd) {
  u32 w = xd[threadIdx.x & 63];
  u32 e = (w >> 8) & 0x7fu;
  unsigned long long m = __ballot((e >= 0x38u) && (e <= 0x41u));
  return __popcll(m) > 32;
}
// async 16B/lane global->LDS (dest = wave-uniform base + lane*16)
__device__ __forceinline__ void gld16(const void* g, void* l) {
  __builtin_amdgcn_global_load_lds((const __attribute__((address_space(1))) u32*)g,
                                   (__attribute__((address_space(3))) u32*)l, 16, 0, 0);
}

// ---------- prologue: x transpose (0..2047) + Wq/Wk/Wv prep (2048..2239) + optional Wo (2240..2303) ----------
__global__ void __launch_bounds__(256) prologue_kernel(const void* __restrict__ xin,
                                                       u16* __restrict__ xT,
                                                       const void* __restrict__ W0, const void* __restrict__ W1,
                                                       const void* __restrict__ W2, const void* __restrict__ b0,
                                                       const void* __restrict__ b1, const void* __restrict__ b2,
                                                       u16* __restrict__ wdst, float* __restrict__ bdst,
                                                       const void* __restrict__ Wo, const void* __restrict__ bo,
                                                       const void* __restrict__ gm, u16* __restrict__ wodst,
                                                       float* __restrict__ bodst) {
  const int blk = blockIdx.x;
  const int tid = threadIdx.x;
  const int isbf = detect_bf16((const u32*)xin);
  if (blk < 2048) {
    const int s0 = (blk & 15) * 64, c0 = ((blk >> 4) & 3) * 64, b = blk >> 6;
    __shared__ u16 T[64][72];  // [c-local][s-local], +8 pad
    if (isbf) {
      const u16* xp = (const u16*)xin;
      for (int t = tid; t < 512; t += 256) {
        int r = t >> 3, off = (t & 7) * 8;
        *(uint4*)&T[r][off] = *(const uint4*)(xp + ((size_t)(b * 256 + c0 + r)) * 1024 + s0 + off);
      }
    } else {
      const float* xp = (const float*)xin;
      for (int t = tid; t < 512; t += 256) {
        int r = t >> 3, off = (t & 7) * 8;
        const float* s = xp + ((size_t)(b * 256 + c0 + r)) * 1024 + s0 + off;
#pragma unroll
        for (int u = 0; u < 8; u++) T[r][off + u] = f2bf(s[u]);
      }
    }
    __syncthreads();
    for (int t = tid; t < 512; t += 256) {
      int r = t >> 3, off = (t & 7) * 8;   // r = s-local, off = c-local
      union { u16 h[8]; uint4 v; } pk;
#pragma unroll
      for (int u = 0; u < 8; u++) pk.h[u] = T[off + u][r];
      *(uint4*)(xT + ((size_t)(b * 1024 + s0 + r)) * 256 + c0 + off) = pk.v;
    }
  } else if (blk < 2240) {
    const int g = blk - 2048;            // 192 blocks: 64 per weight
    const int which = g >> 6, bk = g & 63;
    const void* Ws = which == 0 ? W0 : which == 1 ? W1 : W2;
    const void* bs = which == 0 ? b0 : which == 1 ? b1 : b2;
    const int idx = bk * 1024 + tid * 4;
    u16* dst = wdst + which * 65536 + idx;
    if (isbf) {
      *(ushort4*)dst = *(const ushort4*)((const u16*)Ws + idx);
    } else {
      const float* s = (const float*)Ws + idx;
      ushort4 o; o.x = f2bf(s[0]); o.y = f2bf(s[1]); o.z = f2bf(s[2]); o.w = f2bf(s[3]);
      *(ushort4*)dst = o;
    }
    if (bk == 0) {
      bdst[which * 256 + tid] = isbf ? bf2f(((const u16*)bs)[tid]) : ((const float*)bs)[tid];
    }
  } else {
    const int g = blk - 2240;            // 64 blocks: Wo
    const int idx = g * 1024 + tid * 4;
    if (isbf) {
      *(ushort4*)(wodst + idx) = *(const ushort4*)((const u16*)Wo + idx);
    } else {
      const float* s = (const float*)Wo + idx;
      ushort4 o; o.x = f2bf(s[0]); o.y = f2bf(s[1]); o.z = f2bf(s[2]); o.w = f2bf(s[3]);
      *(ushort4*)(wodst + idx) = o;
    }
    if (g == 0) {
      bodst[tid] = isbf ? bf2f(((const u16*)bo)[tid]) : ((const float*)bo)[tid];
      if (tid == 0) bodst[256] = isbf ? bf2f(((const u16*)gm)[0]) : ((const float*)gm)[0];
    }
  }
}

// ---------- Wo prep fallback (when ws tail unavailable; runs after attn) ----------
__global__ void __launch_bounds__(256) prep_o(const void* __restrict__ Wo, const void* __restrict__ bo,
                                              const void* __restrict__ gm, u16* __restrict__ wdst,
                                              float* __restrict__ bdst, const u32* __restrict__ xdet) {
  const int isbf = detect_bf16(xdet);
  const int idx = blockIdx.x * 1024 + threadIdx.x * 4;
  if (isbf) {
    *(ushort4*)(wdst + idx) = *(const ushort4*)((const u16*)Wo + idx);
  } else {
    const float* s = (const float*)Wo + idx;
    ushort4 o; o.x = f2bf(s[0]); o.y = f2bf(s[1]); o.z = f2bf(s[2]); o.w = f2bf(s[3]);
    *(ushort4*)(wdst + idx) = o;
  }
  if (blockIdx.x == 0) {
    int t = threadIdx.x;
    bdst[t] = isbf ? bf2f(((const u16*)bo)[t]) : ((const float*)bo)[t];
    if (t == 0) bdst[256] = isbf ? bf2f(((const u16*)gm)[0]) : ((const float*)gm)[0];
  }
}

// ---------- fused QKV projection, BK=64, unified orientation: D[m=c][n=s] ----------
// A = W (rows c), B = xT (rows s) for ALL three projections. The register dim
// (quad*4+r) is now c -> for Q/K head-packed (b,h,s,32) the 4 consecutive dh
// form one contiguous ushort4 store (was 4 scalar u16 at 64B stride).
// V store (b,c,s) unchanged-scalar (n=s is the lane dim there).
__global__ void __launch_bounds__(256) qkv_gemm(const u16* __restrict__ xT,
                                                const u16* __restrict__ Wall,
                                                const float* __restrict__ ball,
                                                u16* __restrict__ Qb, u16* __restrict__ Kb,
                                                u16* __restrict__ Vb) {
  const int z = blockIdx.z, b = z / 3, which = z - b * 3;
  const int tid = threadIdx.x, lane = tid & 63, wave = tid >> 6;
  const int quad = lane >> 4, l16 = lane & 15;
  const int wm = wave >> 1, wn = wave & 1;
  const u16* xb = xT + (size_t)b * 262144;
  const u16* W = Wall + which * 65536;
  const int m0 = blockIdx.y * 128;   // c tile (2)
  const int n0 = blockIdx.x * 128;   // s tile (8)

  __shared__ u16 Ash[8192], Bsh[8192];   // 128 rows x 64 (128B rows), k-granule swizzled
  f32x4 acc[4][4];
#pragma unroll
  for (int i = 0; i < 4; i++)
#pragma unroll
    for (int j = 0; j < 4; j++) acc[i][j] = (f32x4){0.f, 0.f, 0.f, 0.f};

  const int srow = lane >> 3;
  const int sgc = (lane & 7) ^ (srow & 7);   // pre-swizzled source k-granule
  for (int k0 = 0; k0 < 256; k0 += 64) {
    __syncthreads();   // WAR: prior frag reads done before restage lands
#pragma unroll
    for (int p = 0; p < 4; p++) {
      const int row = p * 32 + wave * 8;
      gld16(W  + (size_t)(m0 + row + srow) * 256 + k0 + sgc * 8, &Ash[row * 64 + lane * 8]);
      gld16(xb + (size_t)(n0 + row + srow) * 256 + k0 + sgc * 8, &Bsh[row * 64 + lane * 8]);
    }
    __syncthreads();   // drains vmcnt before barrier
#pragma unroll
    for (int kk = 0; kk < 2; kk++) {
      bf16x8 av[4], bv[4];
      const int rg = (kk * 4 + quad) ^ (l16 & 7);   // swizzled read granule
#pragma unroll
      for (int i = 0; i < 4; i++) av[i] = *(const bf16x8*)&Ash[(wm * 64 + i * 16 + l16) * 64 + rg * 8];
#pragma unroll
      for (int j = 0; j < 4; j++) bv[j] = *(const bf16x8*)&Bsh[(wn * 64 + j * 16 + l16) * 64 + rg * 8];
#pragma unroll
      for (int i = 0; i < 4; i++)
#pragma unroll
        for (int j = 0; j < 4; j++)
          acc[i][j] = __builtin_amdgcn_mfma_f32_16x16x32_bf16(av[i], bv[j], acc[i][j], 0, 0, 0);
    }
  }

  const float* bias = ball + which * 256;
  const float scale = (which == 0) ? 0.25503486f : 1.0f;  // (1/sqrt(32))*log2(e) folded into Q
#pragma unroll
  for (int i = 0; i < 4; i++) {
#pragma unroll
    for (int j = 0; j < 4; j++) {
      const int mb = m0 + wm * 64 + i * 16 + quad * 4;   // c, 4-consecutive via r
      const int n = n0 + wn * 64 + j * 16 + l16;         // s
      if (which < 2) {
        u16* D = (which ? Kb : Qb) + (size_t)b * 262144;
        ushort4 st;
        st.x = f2bf((acc[i][j][0] + bias[mb + 0]) * scale);
        st.y = f2bf((acc[i][j][1] + bias[mb + 1]) * scale);
        st.z = f2bf((acc[i][j][2] + bias[mb + 2]) * scale);
        st.w = f2bf((acc[i][j][3] + bias[mb + 3]) * scale);
        // head-packed (h, s, dh); mb%4==0 so the quad stays inside one head
        *(ushort4*)(D + (size_t)(mb >> 5) * 32768 + (size_t)n * 32 + (mb & 31)) = st;
      } else {
        u16* D = Vb + (size_t)b * 262144;
#pragma unroll
        for (int r = 0; r < 4; r++) {
          const int m = mb + r;
          D[(size_t)m * 1024 + n] = f2bf(acc[i][j][r] + bias[m]);
        }
      }
    }
  }
}

// ---------- fused attention v12: lsum via MFMA (ones B-operand) ----------
// R5 falsified the occupancy theory (45% occ, slower): VALU ISSUE is binding.
// The lsum reduction tree (16 adds/tt + 16 epilogue shfls) moves to the matrix
// pipe: lacc = mfma(pk, ones, lacc) -- same D-shape as oacc, so lacc[r] is the
// row-sum for exactly oacc[r]'s q. Epilogue: oacc[r]/lacc[r], no shuffles.
__global__ void __launch_bounds__(512) attn_kernel(const u16* __restrict__ Q,
                                                   const u16* __restrict__ K,
                                                   const u16* __restrict__ V,
                                                   u16* __restrict__ O) {
  const int blk = blockIdx.x;
  const int qc = blk >> 8, bh = blk & 255;
  const int b = bh >> 3, h = bh & 7;
  const int tid = threadIdx.x, wave = tid >> 6, lane = tid & 63;
  const int hi = lane >> 5, l32 = lane & 31;
  __shared__ __align__(16) u16 Ksh[2][128 * 32];  // [t][d] granule-swizzled
  __shared__ __align__(16) u16 Vsh[2][32 * 128];  // [d][t] granule col ^= (d&15)
  const u16* Qg = Q + (size_t)b * 262144 + (size_t)h * 32768;  // (b,h,s,32)
  const u16* Kg = K + (size_t)b * 262144 + (size_t)h * 32768;  // (b,h,s,32)
  const u16* Vg = V + (size_t)b * 262144 + (size_t)h * 32768;  // (b,h,dh,s)
  const int qw = qc * 256 + wave * 32;   // this wave's 32 q rows

  // Q frags (B-operand): lane n=l32 holds Q[q=qw+l32][d = ks*16 + hi*8 + j]
  bf16x8 qf[2];
#pragma unroll
  for (int ks = 0; ks < 2; ks++)
    qf[ks] = *(const bf16x8*)(Qg + (size_t)(qw + l32) * 32 + ks * 16 + hi * 8);

  // K staging: this lane's granule Gg; location Gg must hold K[t(Gg)][8*s(Gg)..+7]
  const int Gg = wave * 64 + lane;
  const int th = Gg >> 3;
  const int uu = (Gg & 7) ^ (th & 7);
  const u16* ksrc = Kg + (size_t)(th * 2 + (uu >> 2)) * 32 + (uu & 3) * 8;
  u16* kdst0 = &Ksh[0][Gg * 8];
  u16* kdst1 = &Ksh[1][Gg * 8];
  // V staging: granule tid holds V[d = tid>>4][8*((tid&15)^(d&15)) ..+7]
  const int vd = tid >> 4;
  const u16* vsrc = Vg + (size_t)vd * 1024 + ((tid & 15) ^ (vd & 15)) * 8;
  u16* vdst0 = &Vsh[0][tid * 8];
  u16* vdst1 = &Vsh[1][tid * 8];

  // kf read byte-offsets (A-operand, lane m = t = tt*32+l32, k-half ks): +tt*2048
  const int kkey = (l32 >> 1) & 7;
  const int kb0 = (l32 >> 1) * 128 + (((((l32 & 1) << 2) | 0 | hi) ^ kkey) << 4);
  const int kb1 = (l32 >> 1) * 128 + (((((l32 & 1) << 2) | 2 | hi) ^ kkey) << 4);
  // vf read byte-offsets computed inline per tt (rolled loop; no runtime-indexed array)
  const int vm0 = ((l32 & 3) ^ hi) << 4;
  const int vm1 = ((l32 & 3) ^ (2 | hi)) << 4;

  f32x16 oacc;
#pragma unroll
  for (int r = 0; r < 16; r++) oacc[r] = 0.f;
  f32x16 lacc;   // row-sum accumulator: lacc[r] = sum_t P[q(r)][t]
#pragma unroll
  for (int r = 0; r < 16; r++) lacc[r] = 0.f;
  f32x16 zro;    // persistent zero C-operand for QK^T (never written)
#pragma unroll
  for (int r = 0; r < 16; r++) zro[r] = 0.f;
  bf16x8 ones;   // all-ones B-operand for the row-sum MFMA
#pragma unroll
  for (int r = 0; r < 8; r++) ones[r] = (short)0x3F80;

  // prologue: stage tile 0
  gld16(ksrc, kdst0);
  gld16(vsrc, vdst0);
  __syncthreads();

#pragma unroll 1
  for (int kt = 0; kt < 8; kt++) {
    const int c = kt & 1;
    if (kt < 7) {   // issue next tile into the other buffer; drained at loop-end barrier
      gld16(ksrc + (size_t)(kt + 1) * 4096, c ? kdst0 : kdst1);   // 128 t-rows x 32
      gld16(vsrc + (kt + 1) * 128,          c ? vdst0 : vdst1);
    }
    const char* Kb = (const char*)&Ksh[c][0];
    const char* Vb = (const char*)&Vsh[c][0];
#pragma unroll 1
    for (int tt = 0; tt < 4; tt++) {
      const int vbt = l32 * 256 + (((l32 & 12) ^ (tt << 2)) << 4);
      const bf16x8 kf0 = *(const bf16x8*)(Kb + tt * 2048 + kb0);
      const bf16x8 kf1 = *(const bf16x8*)(Kb + tt * 2048 + kb1);
      const bf16x8 vf0 = *(const bf16x8*)(Vb + vbt + vm0);
      const bf16x8 vf1 = *(const bf16x8*)(Vb + vbt + vm1);
      __builtin_amdgcn_s_setprio(1);
      f32x16 sf = __builtin_amdgcn_mfma_f32_32x32x16_bf16(kf0, qf[0], zro, 0, 0, 0);
      sf = __builtin_amdgcn_mfma_f32_32x32x16_bf16(kf1, qf[1], sf, 0, 0, 0);
      __builtin_amdgcn_s_setprio(0);
      // ---- first 16 t of the tile (groups g0 = sf[0:3], g1 = sf[4:7]) ----
      {
        const float p0 = __builtin_amdgcn_exp2f(sf[0]);
        const float p1 = __builtin_amdgcn_exp2f(sf[1]);
        const float p2 = __builtin_amdgcn_exp2f(sf[2]);
        const float p3 = __builtin_amdgcn_exp2f(sf[3]);
        const float p4 = __builtin_amdgcn_exp2f(sf[4]);
        const float p5 = __builtin_amdgcn_exp2f(sf[5]);
        const float p6 = __builtin_amdgcn_exp2f(sf[6]);
        const float p7 = __builtin_amdgcn_exp2f(sf[7]);
        u32 wa, wb, wc, wd;
        asm("v_cvt_pk_bf16_f32 %0, %1, %2" : "=v"(wa) : "v"(p0), "v"(p1));
        asm("v_cvt_pk_bf16_f32 %0, %1, %2" : "=v"(wb) : "v"(p2), "v"(p3));
        asm("v_cvt_pk_bf16_f32 %0, %1, %2" : "=v"(wc) : "v"(p4), "v"(p5));
        asm("v_cvt_pk_bf16_f32 %0, %1, %2" : "=v"(wd) : "v"(p6), "v"(p7));
#if __has_builtin(__builtin_amdgcn_permlane32_swap)
        auto s0 = __builtin_amdgcn_permlane32_swap((int)wc, (int)wa, false, false);
        auto s1 = __builtin_amdgcn_permlane32_swap((int)wd, (int)wb, false, false);
        union { int w[4]; bf16x8 v; } pk;
        pk.w[0] = s0[1]; pk.w[1] = s1[1]; pk.w[2] = s0[0]; pk.w[3] = s1[0];
#else
        const u32 xa = __shfl_xor((int)wa, 32), xb = __shfl_xor((int)wb, 32);
        const u32 xc = __shfl_xor((int)wc, 32), xd = __shfl_xor((int)wd, 32);
        union { u32 w[4]; bf16x8 v; } pk;
        pk.w[0] = hi ? xc : wa; pk.w[1] = hi ? xd : wb;
        pk.w[2] = hi ? wc : xa; pk.w[3] = hi ? wd : xb;
#endif
        __builtin_amdgcn_s_setprio(1);
        oacc = __builtin_amdgcn_mfma_f32_32x32x16_bf16(pk.v, vf0, oacc, 0, 0, 0);
        lacc = __builtin_amdgcn_mfma_f32_32x32x16_bf16(pk.v, ones, lacc, 0, 0, 0);
        __builtin_amdgcn_s_setprio(0);
      }
      // ---- second 16 t of the tile (groups g2 = sf[8:11], g3 = sf[12:15]) ----
      {
        const float p0 = __builtin_amdgcn_exp2f(sf[8]);
        const float p1 = __builtin_amdgcn_exp2f(sf[9]);
        const float p2 = __builtin_amdgcn_exp2f(sf[10]);
        const float p3 = __builtin_amdgcn_exp2f(sf[11]);
        const float p4 = __builtin_amdgcn_exp2f(sf[12]);
        const float p5 = __builtin_amdgcn_exp2f(sf[13]);
        const float p6 = __builtin_amdgcn_exp2f(sf[14]);
        const float p7 = __builtin_amdgcn_exp2f(sf[15]);
        u32 wa, wb, wc, wd;
        asm("v_cvt_pk_bf16_f32 %0, %1, %2" : "=v"(wa) : "v"(p0), "v"(p1));
        asm("v_cvt_pk_bf16_f32 %0, %1, %2" : "=v"(wb) : "v"(p2), "v"(p3));
        asm("v_cvt_pk_bf16_f32 %0, %1, %2" : "=v"(wc) : "v"(p4), "v"(p5));
        asm("v_cvt_pk_bf16_f32 %0, %1, %2" : "=v"(wd) : "v"(p6), "v"(p7));
#if __has_builtin(__builtin_amdgcn_permlane32_swap)
        auto s0 = __builtin_amdgcn_permlane32_swap((int)wc, (int)wa, false, false);
        auto s1 = __builtin_amdgcn_permlane32_swap((int)wd, (int)wb, false, false);
        union { int w[4]; bf16x8 v; } pk;
        pk.w[0] = s0[1]; pk.w[1] = s1[1]; pk.w[2] = s0[0]; pk.w[3] = s1[0];
#else
        const u32 xa = __shfl_xor((int)wa, 32), xb = __shfl_xor((int)wb, 32);
        const u32 xc = __shfl_xor((int)wc, 32), xd = __shfl_xor((int)wd, 32);
        union { u32 w[4]; bf16x8 v; } pk;
        pk.w[0] = hi ? xc : wa; pk.w[1] = hi ? xd : wb;
        pk.w[2] = hi ? wc : xa; pk.w[3] = hi ? wd : xb;
#endif
        __builtin_amdgcn_s_setprio(1);
        oacc = __builtin_amdgcn_mfma_f32_32x32x16_bf16(pk.v, vf1, oacc, 0, 0, 0);
        lacc = __builtin_amdgcn_mfma_f32_32x32x16_bf16(pk.v, ones, lacc, 0, 0, 0);
        __builtin_amdgcn_s_setprio(0);
      }
    }
    if (kt < 7) __syncthreads();   // drains vmcnt (prefetch) + WAR for restage
  }

  // epilogue: lacc[r] is the row-sum for oacc[r]'s q -- no shuffles needed
  u16* Og = O + (size_t)(b * 1024 + qw) * 256 + h * 32 + l32;
#pragma unroll
  for (int r = 0; r < 16; r++) {
    const int qo = (r & 3) + 8 * (r >> 2) + 4 * hi;   // oacc row -> q offset
    Og[(size_t)qo * 256] = f2bf(oacc[r] / lacc[r]);
  }
}

// ---------- out projection + residual: out = 2x + g*(Wo.O + bo) ----------
// Orientation: D[m=s][n=c] so the per-lane register dim (4 consecutive s) is
// contiguous in out(c,s) -> float4 x-loads and float4 stores on the 256MB f32
// stream. Tiles 128(s) x 64(c), grid (8,4,32) = 1024.
__global__ void __launch_bounds__(256) out_gemm(const u16* __restrict__ WoB,
                                                const float* __restrict__ bg,
                                                const u16* __restrict__ Ob,
                                                const void* __restrict__ xin,
                                                void* __restrict__ outp,
                                                const u32* __restrict__ xdet) {
  const int b = blockIdx.z;
  const int m0 = blockIdx.x * 128;   // s tile (8)
  const int n0 = blockIdx.y * 64;    // c tile (4)
  const int tid = threadIdx.x, lane = tid & 63, wave = tid >> 6;
  const int quad = lane >> 4, l16 = lane & 15;
  const int wm = wave >> 1, wn = wave & 1;   // per wave: 64 m x 32 n
  const int isbf = detect_bf16(xdet);
  const u16* Ab = Ob + (size_t)b * 262144;   // A rows = s (k-major 256)
  __shared__ u16 Ash[8192], Bsh[4096];       // A 128x64, B 64x64 (swizzled granules)
  f32x4 acc[4][2];
#pragma unroll
  for (int i = 0; i < 4; i++)
#pragma unroll
    for (int j = 0; j < 2; j++) acc[i][j] = (f32x4){0.f, 0.f, 0.f, 0.f};

  const int srow = lane >> 3;
  const int sgc = (lane & 7) ^ (srow & 7);   // pre-swizzled source k-granule
  for (int k0 = 0; k0 < 256; k0 += 64) {
    __syncthreads();
#pragma unroll
    for (int p = 0; p < 4; p++) {
      const int row = p * 32 + wave * 8;
      gld16(Ab + (size_t)(m0 + row + srow) * 256 + k0 + sgc * 8, &Ash[row * 64 + lane * 8]);
    }
#pragma unroll
    for (int p = 0; p < 2; p++) {
      const int row = p * 32 + wave * 8;
      gld16(WoB + (size_t)(n0 + row + srow) * 256 + k0 + sgc * 8, &Bsh[row * 64 + lane * 8]);
    }
    __syncthreads();
#pragma unroll
    for (int kk = 0; kk < 2; kk++) {
      bf16x8 av[4], bv[2];
      const int rg = (kk * 4 + quad) ^ (l16 & 7);   // swizzled read granule
#pragma unroll
      for (int i = 0; i < 4; i++) av[i] = *(const bf16x8*)&Ash[(wm * 64 + i * 16 + l16) * 64 + rg * 8];
#pragma unroll
      for (int j = 0; j < 2; j++) bv[j] = *(const bf16x8*)&Bsh[(wn * 32 + j * 16 + l16) * 64 + rg * 8];
#pragma unroll
      for (int i = 0; i < 4; i++)
#pragma unroll
        for (int j = 0; j < 2; j++)
          acc[i][j] = __builtin_amdgcn_mfma_f32_16x16x32_bf16(av[i], bv[j], acc[i][j], 0, 0, 0);
    }
  }

  const float g = bg[256];
#pragma unroll
  for (int i = 0; i < 4; i++) {
#pragma unroll
    for (int j = 0; j < 2; j++) {
      const int mb = m0 + wm * 64 + i * 16 + quad * 4;   // s, 4-consecutive via r
      const int n = n0 + wn * 32 + j * 16 + l16;         // c
      const float bc = bg[n];
      const size_t gi = (size_t)b * 262144 + (size_t)n * 1024 + mb;
      if (isbf) {
        const ushort4 xv = *(const ushort4*)((const u16*)xin + gi);
        ushort4 st;
        st.x = f2bf(2.f * bf2f(xv.x) + g * (acc[i][j][0] + bc));
        st.y = f2bf(2.f * bf2f(xv.y) + g * (acc[i][j][1] + bc));
        st.z = f2bf(2.f * bf2f(xv.z) + g * (acc[i][j][2] + bc));
        st.w = f2bf(2.f * bf2f(xv.w) + g * (acc[i][j][3] + bc));
        *(ushort4*)((u16*)outp + gi) = st;
      } else {
        const float4 xv = *(const float4*)((const float*)xin + gi);
        float4 st;
        st.x = 2.f * xv.x + g * (acc[i][j][0] + bc);
        st.y = 2.f * xv.y + g * (acc[i][j][1] + bc);
        st.z = 2.f * xv.z + g * (acc[i][j][2] + bc);
        st.w = 2.f * xv.w + g * (acc[i][j][3] + bc);
        *(float4*)((float*)outp + gi) = st;
      }
    }
  }
}

// ---------- launcher ----------
extern "C" void kernel_launch(void* const* d_in, const int* in_sizes, int n_in,
                              void* d_out, int out_size, void* d_ws, size_t ws_size,
                              hipStream_t stream) {
  const void* x  = d_in[0];
  const void* Wq = d_in[1]; const void* bq = d_in[2];
  const void* Wk = d_in[3]; const void* bk = d_in[4];
  const void* Wv = d_in[5]; const void* bv = d_in[6];
  const void* Wo = d_in[7]; const void* bo = d_in[8];
  const void* gm = d_in[9];

  u16* ws = (u16*)d_ws;
  u16* xT = ws;            // (b,s,c) bf16; reused as O after V-proj
  u16* Qb = ws + NT;       // (b,h,s,32), scale*log2e folded
  u16* Kb = ws + 2 * NT;   // (b,h,s,32)
  u16* Vb = ws + 3 * NT;   // (b,256,s) == (b,h,dh,s)
  u16* Ob = xT;
  const u32* xdet = (const u32*)x;

  // d_out doubles as QKV-weight scratch until out_gemm rewrites it fully
  u16* WqkvB = (u16*)d_out;                              // 3 x 65536 u16
  float* bqkvF = (float*)((u16*)d_out + 196608);         // 768 f32

  // Wo scratch: ws tail if it fits (prep folded into prologue), else dead-Q fallback
  const bool tail = ws_size >= (size_t)(4 * NT + 66048) * 2;
  u16* WoB = tail ? (ws + 4 * NT) : Qb;
  float* boF = tail ? (float*)(ws + 4 * NT + 65536) : (float*)(Qb + 65536);

  prologue_kernel<<<dim3(tail ? 2304 : 2240), 256, 0, stream>>>(
      x, xT, Wq, Wk, Wv, bq, bk, bv, WqkvB, bqkvF, Wo, bo, gm, WoB, boF);
  qkv_gemm<<<dim3(8, 2, 96), 256, 0, stream>>>(xT, WqkvB, bqkvF, Qb, Kb, Vb);
  attn_kernel<<<dim3(1024), 512, 0, stream>>>(Qb, Kb, Vb, Ob);
  if (!tail) prep_o<<<dim3(64), 256, 0, stream>>>(Wo, bo, gm, WoB, boF, xdet);
  out_gemm<<<dim3(8, 4, 32), 256, 0, stream>>>(WoB, boF, Ob, x, d_out, xdet);
}